// Round 7
// baseline (3207.320 us; speedup 1.0000x reference)
//
#include <hip/hip_runtime.h>
#include <stdint.h>

// LSTM (packed sequence) on MI355X — round 7.
// T=512, B=64, D=512, H=512. out[t,b,:] = masked h_t.
//
// PRODUCER/CONSUMER WG SPECIALIZATION (one cooperative launch, 256 WGs):
//   H-WGs (0..127): recurrence only. 4 groups (16 batch rows) x 32 jblk.
//     Per step: poll h_{t-1} (tagged) + xg(t) (tagged) -> h-GEMM (192 MFMA,
//     M=16 fully used) -> cell -> tagged h store + step counter.
//   X-WGs (128..255): partner 1:1 with H-WGs. Compute xg(t) = x_t@Wx^T + b
//     for their (group, jblk) slice, running up to 4 steps AHEAD, publishing
//     into a 4-deep ring as tagged bf16(hi,lo) pairs scaled by 1/32
//     (|p| clamped to 63.75 => |v| < 2 => bit14 of both halves = 0 -> free
//     2-bit step tag, the same SELF-DESCRIBING transport proven in R4-R6).
//     Ring overwrite gated on partner counter >= t-3 (tag distance 4).
//   This halves total MFMA issue per step (no M-duplication, x off the
//   serial path) without needing workspace for the full xg (10.75 MB total).
//   Fallback: verbatim R4 kernel if ws_size < 10.75 MB.
//   bf16 3-split MFMA (hi/lo): fp32-class accuracy (absmax ~4e-3, R1-R6).

#define TT 512
#define BB 64
#define DD 512
#define HH 512
#define NTHR 512
#define NWG 256
#define NPAIR 128
#define GR 16
// fallback path (R4)
#define NWG4 256
#define GR4 8

typedef short short8 __attribute__((ext_vector_type(8)));
typedef float f32x4 __attribute__((ext_vector_type(4)));

__device__ __forceinline__ uint16_t bf16_rne(float f) {
  uint32_t u = __float_as_uint(f);
  u += 0x7fffu + ((u >> 16) & 1u);
  return (uint16_t)(u >> 16);
}

__device__ __forceinline__ void split2(float f, uint16_t &hi, uint16_t &lo) {
  uint16_t h = bf16_rne(f);
  hi = h;
  lo = bf16_rne(f - __uint_as_float(((uint32_t)h) << 16));
}

__device__ __forceinline__ float sigf(float v) { return 1.0f / (1.0f + __expf(-v)); }
__device__ __forceinline__ float tanh_(float v) {
  return 1.0f - 2.0f / (__expf(2.0f * v) + 1.0f);
}

// Build MFMA B-fragment buffer from W [2048][512] (row-major, k contiguous).
// B-frag lane layout for mfma_f32_16x16x32_bf16: col = lane&15,
// k = ks*32 + (lane>>4)*8 + j (8 contiguous k per lane).
__global__ void build_frags(const float* __restrict__ W, uint32_t* __restrict__ frag) {
  const int tid = blockIdx.x * 256 + threadIdx.x;   // 0..131071
  const int lane = tid & 63;
  const int ks = (tid >> 6) & 15;
  const int nblk = tid >> 10;                        // 0..127
  const int col = nblk * 16 + (lane & 15);
  const int k0 = ks * 32 + ((lane >> 4) << 3);
  const float* src = W + (size_t)col * 512 + k0;
  float4 a = *(const float4*)(src);
  float4 b = *(const float4*)(src + 4);
  float v[8] = {a.x, a.y, a.z, a.w, b.x, b.y, b.z, b.w};
  uint32_t hw[4], lw[4];
#pragma unroll
  for (int j = 0; j < 4; ++j) {
    uint16_t h0, l0, h1, l1;
    split2(v[2 * j], h0, l0);
    split2(v[2 * j + 1], h1, l1);
    hw[j] = (uint32_t)h0 | ((uint32_t)h1 << 16);
    lw[j] = (uint32_t)l0 | ((uint32_t)l1 << 16);
  }
  uint4* dst = (uint4*)(frag + (size_t)tid * 8);
  dst[0] = make_uint4(hw[0], hw[1], hw[2], hw[3]);
  dst[1] = make_uint4(lw[0], lw[1], lw[2], lw[3]);
}

__global__ __launch_bounds__(NTHR, 2) void lstm3(
    const float* __restrict__ x, const int* __restrict__ len,
    const float* __restrict__ bias, const uint32_t* __restrict__ fragWx,
    const uint32_t* __restrict__ fragWh, uint32_t* __restrict__ h_pair,
    uint32_t* __restrict__ xacc, uint32_t* __restrict__ cnts,
    float* __restrict__ out) {
  const int tid = threadIdx.x;
  const int lane = tid & 63;
  const int wave = tid >> 6;      // 0..7
  const int gp = wave >> 1;       // gate 0..3 (i,f,c,o)
  const int kh = wave & 1;        // K half
  const bool isH = blockIdx.x < NPAIR;
  const int pid = isH ? blockIdx.x : blockIdx.x - NPAIR;
  const int group = pid & 3;
  const int jblk = pid >> 2;      // 0..31
  const int b0 = group * GR;
  const int j0 = jblk << 4;
  uint32_t* hbase = h_pair + (size_t)group * 2 * (GR * HH);
  unsigned long long* xb64 = (unsigned long long*)(xacc + (size_t)pid * 4096);

  __shared__ uint16_t AH[GR * 512];   // 16 KB
  __shared__ uint16_t AL[GR * 512];   // 16 KB
  __shared__ float ex[8][GR][16];     // 8 KB
  __shared__ float xex[GR][64];       // 4 KB (H only)
  __shared__ float c_st[GR][16];
  __shared__ float h_st[GR][16];
  __shared__ float bias_l[4][16];     // X only
  __shared__ int len_l[GR];

  const int arow = lane & 15;
  const int achk = (lane >> 4) << 4;
  const int axr = (arow & 7) << 4;
  const char* rowH = (const char*)AH + arow * 1024;
  const char* rowL = (const char*)AL + arow * 1024;

  const uint64_t MK2 = 0x4000400040004000ull;
  const uint32_t CM = ~0x40004000u;

  if (isH) {
    // ====================== H role: recurrence ======================
    if (tid < 256) {
      c_st[tid >> 4][tid & 15] = 0.0f;
      h_st[tid >> 4][tid & 15] = 0.0f;
    }
    if (tid < GR) len_l[tid] = len[b0 + tid];

    short8 bhh[8], bhl[8];
    {
      const int nblk = gp * 32 + jblk;
#pragma unroll
      for (int ksl = 0; ksl < 8; ++ksl) {
        const size_t idx = ((size_t)(nblk * 16 + kh * 8 + ksl) * 64 + lane) * 8;
        bhh[ksl] = __builtin_bit_cast(short8, *(const uint4*)(fragWh + idx));
        bhl[ksl] = __builtin_bit_cast(short8, *(const uint4*)(fragWh + idx + 4));
      }
    }

    const int prow = tid >> 5;          // poll row 0..15
    const int pc0 = tid & 31;           // chunk ids pc0, pc0+32
    const int brow = tid >> 4;          // cell coords
    const int jc = tid & 15;

    for (int t = 0; t < TT; ++t) {
      const int rbuf = t & 1;
      const int wbuf = rbuf ^ 1;

      // tags
      const uint32_t tagh = (((uint32_t)(t - 1)) >> 1) & 3u;
      const uint32_t EHd = ((tagh & 1u) << 14) | ((tagh >> 1) << 30);
      const uint64_t EH2 = ((uint64_t)EHd << 32) | EHd;
      const uint32_t tagx = (((uint32_t)t) >> 1) & 3u;
      const uint32_t EXd = ((tagx & 1u) << 14) | ((tagx >> 1) << 30);
      const uint64_t EX2 = ((uint64_t)EXd << 32) | EXd;

      const unsigned long long* hb64 =
          (const unsigned long long*)(hbase + (size_t)rbuf * (GR * HH));
      const unsigned long long* hp0 = hb64 + prow * 256 + pc0 * 4;
      const unsigned long long* hp1 = hp0 + 128;   // chunk pc0+32
      const unsigned long long* xp = xb64 + (size_t)(t & 3) * 512 + tid;

      uint64_t w0, w1, w2, w3, w4, w5, w6, w7, wx;
      if (t > 0) {
        for (;;) {
          w0 = __hip_atomic_load(hp0 + 0, __ATOMIC_RELAXED, __HIP_MEMORY_SCOPE_AGENT);
          w1 = __hip_atomic_load(hp0 + 1, __ATOMIC_RELAXED, __HIP_MEMORY_SCOPE_AGENT);
          w2 = __hip_atomic_load(hp0 + 2, __ATOMIC_RELAXED, __HIP_MEMORY_SCOPE_AGENT);
          w3 = __hip_atomic_load(hp0 + 3, __ATOMIC_RELAXED, __HIP_MEMORY_SCOPE_AGENT);
          w4 = __hip_atomic_load(hp1 + 0, __ATOMIC_RELAXED, __HIP_MEMORY_SCOPE_AGENT);
          w5 = __hip_atomic_load(hp1 + 1, __ATOMIC_RELAXED, __HIP_MEMORY_SCOPE_AGENT);
          w6 = __hip_atomic_load(hp1 + 2, __ATOMIC_RELAXED, __HIP_MEMORY_SCOPE_AGENT);
          w7 = __hip_atomic_load(hp1 + 3, __ATOMIC_RELAXED, __HIP_MEMORY_SCOPE_AGENT);
          wx = __hip_atomic_load(xp, __ATOMIC_RELAXED, __HIP_MEMORY_SCOPE_AGENT);
          const uint64_t bad = (((w0 ^ EH2) | (w1 ^ EH2) | (w2 ^ EH2) | (w3 ^ EH2) |
                                (w4 ^ EH2) | (w5 ^ EH2) | (w6 ^ EH2) | (w7 ^ EH2) |
                                (wx ^ EX2)) & MK2);
          if (bad == 0ull) break;
        }
      } else {
        for (;;) {
          wx = __hip_atomic_load(xp, __ATOMIC_RELAXED, __HIP_MEMORY_SCOPE_AGENT);
          if (((wx ^ EX2) & MK2) == 0ull) break;
        }
      }

      // unpack h -> AH/AL (chunks pc0 and pc0+32; conflict-free slot spread)
      if (t > 0) {
        const int base = prow * 1024;
        const int swz = (prow & 7) << 4;
        uint32_t d0, d1, d2, d3, d4, d5, d6, d7;
#define UNPK(A, B, C, D, OFF)                                                  \
        d0 = (uint32_t)(A) & CM; d1 = (uint32_t)((A) >> 32) & CM;              \
        d2 = (uint32_t)(B) & CM; d3 = (uint32_t)((B) >> 32) & CM;              \
        d4 = (uint32_t)(C) & CM; d5 = (uint32_t)((C) >> 32) & CM;              \
        d6 = (uint32_t)(D) & CM; d7 = (uint32_t)((D) >> 32) & CM;              \
        *(uint4*)((char*)AH + base + ((OFF) ^ swz)) =                          \
            make_uint4((d0 & 0xFFFFu) | (d1 << 16), (d2 & 0xFFFFu) | (d3 << 16), \
                       (d4 & 0xFFFFu) | (d5 << 16), (d6 & 0xFFFFu) | (d7 << 16)); \
        *(uint4*)((char*)AL + base + ((OFF) ^ swz)) =                          \
            make_uint4((d0 >> 16) | (d1 & 0xFFFF0000u), (d2 >> 16) | (d3 & 0xFFFF0000u), \
                       (d4 >> 16) | (d5 & 0xFFFF0000u), (d6 >> 16) | (d7 & 0xFFFF0000u));
        UNPK(w0, w1, w2, w3, pc0 * 16);
        UNPK(w4, w5, w6, w7, pc0 * 16 + 512);
#undef UNPK
      }
      // unpack xg -> xex (2 fp32 per thread)
      {
        const uint32_t da = (uint32_t)wx & CM;
        const uint32_t db = (uint32_t)(wx >> 32) & CM;
        const int f0 = 2 * tid;
        xex[f0 >> 6][f0 & 63] =
            32.0f * (__uint_as_float(da << 16) + __uint_as_float(da & 0xFFFF0000u));
        xex[f0 >> 6][(f0 & 63) + 1] =
            32.0f * (__uint_as_float(db << 16) + __uint_as_float(db & 0xFFFF0000u));
      }
      __syncthreads();   // B1: AH/AL + xex ready (and len_l/c_st at t=0)

      f32x4 hh = {0.f, 0.f, 0.f, 0.f}, lh = {0.f, 0.f, 0.f, 0.f}, hl = {0.f, 0.f, 0.f, 0.f};
      if (t > 0) {
#pragma unroll
        for (int ksl = 0; ksl < 8; ++ksl) {
          const int off = ((kh * 8 + ksl) * 64 + achk) ^ axr;
          short8 ah = *(const short8*)(rowH + off);
          short8 al = *(const short8*)(rowL + off);
          hh = __builtin_amdgcn_mfma_f32_16x16x32_bf16(ah, bhh[ksl], hh, 0, 0, 0);
          lh = __builtin_amdgcn_mfma_f32_16x16x32_bf16(al, bhh[ksl], lh, 0, 0, 0);
          hl = __builtin_amdgcn_mfma_f32_16x16x32_bf16(ah, bhl[ksl], hl, 0, 0, 0);
        }
      }
      {
        const int crow = (lane >> 4) << 2;
        const int ccol = lane & 15;
#pragma unroll
        for (int r = 0; r < 4; ++r) ex[wave][crow + r][ccol] = hh[r] + lh[r] + hl[r];
      }
      __syncthreads();   // B2: ex ready

      if (tid < 256) {
        const float p0 = ex[0][brow][jc] + ex[1][brow][jc] + xex[brow][jc];
        const float p1 = ex[2][brow][jc] + ex[3][brow][jc] + xex[brow][16 + jc];
        const float p2 = ex[4][brow][jc] + ex[5][brow][jc] + xex[brow][32 + jc];
        const float p3 = ex[6][brow][jc] + ex[7][brow][jc] + xex[brow][48 + jc];
        const float ig = sigf(p0);
        const float fg = sigf(p1);
        const float cc = tanh_(p2);
        const float og = sigf(p3);
        const float co = c_st[brow][jc];
        const float ct = fg * co + ig * cc;
        const float ht = og * tanh_(ct);
        const bool m = (t < len_l[brow]);
        const float cn = m ? ct : co;
        const float hn = m ? ht : h_st[brow][jc];
        c_st[brow][jc] = cn;
        h_st[brow][jc] = hn;
        out[((size_t)t * BB + b0 + brow) * HH + j0 + jc] = m ? ht : 0.0f;
        uint16_t ph, pl;
        split2(hn, ph, pl);   // |hn| <= 1 -> bit14 of both = 0
        const uint32_t tagw = (((uint32_t)t) >> 1) & 3u;
        const uint32_t TB = ((tagw & 1u) << 14) | ((tagw >> 1) << 30);
        __hip_atomic_store(hbase + (size_t)wbuf * (GR * HH) + brow * HH + j0 + jc,
                           ((uint32_t)ph | ((uint32_t)pl << 16)) | TB,
                           __ATOMIC_RELAXED, __HIP_MEMORY_SCOPE_AGENT);
      }
      if (tid == 0)
        __hip_atomic_store(cnts + pid, (uint32_t)(t + 1), __ATOMIC_RELAXED,
                           __HIP_MEMORY_SCOPE_AGENT);
    }
  } else {
    // ====================== X role: xg producer ======================
    if (tid < 64) bias_l[tid >> 4][tid & 15] = bias[(size_t)(tid >> 4) * HH + j0 + (tid & 15)];

    short8 bxh[8], bxl[8];
    {
      const int nblk = gp * 32 + jblk;
#pragma unroll
      for (int ksl = 0; ksl < 8; ++ksl) {
        const size_t idx = ((size_t)(nblk * 16 + kh * 8 + ksl) * 64 + lane) * 8;
        bxh[ksl] = __builtin_bit_cast(short8, *(const uint4*)(fragWx + idx));
        bxl[ksl] = __builtin_bit_cast(short8, *(const uint4*)(fragWx + idx + 4));
      }
    }

    for (int t = 0; t < TT; ++t) {
      // ring gate: slot (t&3) reusable once partner completed step t-4
      if (t >= 4) {
        for (;;) {
          uint32_t c = __hip_atomic_load(cnts + pid, __ATOMIC_RELAXED,
                                         __HIP_MEMORY_SCOPE_AGENT);
          if ((int)c >= t - 3) break;
        }
      }
      // stage x[t] rows b0..b0+15 -> AH/AL
#pragma unroll
      for (int i = 0; i < 4; ++i) {
        const int flat4 = i * 2048 + tid * 4;
        const int row = flat4 >> 9;
        const int col = flat4 & 511;
        float4 v = *(const float4*)(x + ((size_t)t * BB + b0 + row) * DD + col);
        uint16_t h0, l0, h1, l1, h2, l2, h3, l3;
        split2(v.x, h0, l0);
        split2(v.y, h1, l1);
        split2(v.z, h2, l2);
        split2(v.w, h3, l3);
        const int off = row * 1024 + ((col * 2) ^ ((row & 7) << 4));
        *(uint2*)((char*)AH + off) =
            make_uint2((uint32_t)h0 | ((uint32_t)h1 << 16), (uint32_t)h2 | ((uint32_t)h3 << 16));
        *(uint2*)((char*)AL + off) =
            make_uint2((uint32_t)l0 | ((uint32_t)l1 << 16), (uint32_t)l2 | ((uint32_t)l3 << 16));
      }
      __syncthreads();   // B1: tile staged (and bias_l at t=0)

      f32x4 hh = {0.f, 0.f, 0.f, 0.f}, lh = {0.f, 0.f, 0.f, 0.f}, hl = {0.f, 0.f, 0.f, 0.f};
#pragma unroll
      for (int ksl = 0; ksl < 8; ++ksl) {
        const int off = ((kh * 8 + ksl) * 64 + achk) ^ axr;
        short8 ah = *(const short8*)(rowH + off);
        short8 al = *(const short8*)(rowL + off);
        hh = __builtin_amdgcn_mfma_f32_16x16x32_bf16(ah, bxh[ksl], hh, 0, 0, 0);
        lh = __builtin_amdgcn_mfma_f32_16x16x32_bf16(al, bxh[ksl], lh, 0, 0, 0);
        hl = __builtin_amdgcn_mfma_f32_16x16x32_bf16(ah, bxl[ksl], hl, 0, 0, 0);
      }
      {
        const int crow = (lane >> 4) << 2;
        const int ccol = lane & 15;
#pragma unroll
        for (int r = 0; r < 4; ++r) ex[wave][crow + r][ccol] = hh[r] + lh[r] + hl[r];
      }
      __syncthreads();   // B2: ex ready

      // pack 2 gate-preacts per thread -> tagged dword pair -> one u64 store
      {
        const int f0 = 2 * tid;
        const int brow = f0 >> 6;
        const int gc0 = f0 & 63;
        const int gc1 = gc0 + 1;
        const float p0 = ex[(gc0 >> 4) * 2][brow][gc0 & 15] +
                         ex[(gc0 >> 4) * 2 + 1][brow][gc0 & 15] + bias_l[gc0 >> 4][gc0 & 15];
        const float p1 = ex[(gc1 >> 4) * 2][brow][gc1 & 15] +
                         ex[(gc1 >> 4) * 2 + 1][brow][gc1 & 15] + bias_l[gc1 >> 4][gc1 & 15];
        const uint32_t tagw = (((uint32_t)t) >> 1) & 3u;
        const uint32_t TB = ((tagw & 1u) << 14) | ((tagw >> 1) << 30);
        float v0 = p0 * 0.03125f;
        float v1 = p1 * 0.03125f;
        v0 = fminf(fmaxf(v0, -1.9921875f), 1.9921875f);   // keep |v| < 2 -> bit14 = 0
        v1 = fminf(fmaxf(v1, -1.9921875f), 1.9921875f);
        uint16_t h0, l0, h1, l1;
        split2(v0, h0, l0);
        split2(v1, h1, l1);
        const uint32_t da = ((uint32_t)h0 | ((uint32_t)l0 << 16)) | TB;
        const uint32_t db = ((uint32_t)h1 | ((uint32_t)l1 << 16)) | TB;
        __hip_atomic_store(xb64 + (size_t)(t & 3) * 512 + tid,
                           ((uint64_t)db << 32) | da, __ATOMIC_RELAXED,
                           __HIP_MEMORY_SCOPE_AGENT);
      }
    }
  }
}

// ------------------------- fallback: verbatim R4 -------------------------
#define LOAD_XP(tt)                                                            \
  _Pragma("unroll") for (int i = 0; i < 2; ++i) {                              \
    const int flat4 = i * 2048 + tid * 4;                                      \
    const int row = flat4 >> 9;                                                \
    const int col = flat4 & 511;                                               \
    xp[i] = *(const float4*)(x + ((size_t)(tt) * BB + b0 + row) * DD + col);   \
  }

#define STAGE_XP()                                                             \
  _Pragma("unroll") for (int i = 0; i < 2; ++i) {                              \
    const int flat4 = i * 2048 + tid * 4;                                      \
    const int row = flat4 >> 9;                                                \
    const int col = flat4 & 511;                                               \
    uint16_t h0, l0, h1, l1, h2, l2, h3, l3;                                   \
    split2(xp[i].x, h0, l0);                                                   \
    split2(xp[i].y, h1, l1);                                                   \
    split2(xp[i].z, h2, l2);                                                   \
    split2(xp[i].w, h3, l3);                                                   \
    const uint32_t hw0 = (uint32_t)h0 | ((uint32_t)h1 << 16);                  \
    const uint32_t hw1 = (uint32_t)h2 | ((uint32_t)h3 << 16);                  \
    const uint32_t lw0 = (uint32_t)l0 | ((uint32_t)l1 << 16);                  \
    const uint32_t lw1 = (uint32_t)l2 | ((uint32_t)l3 << 16);                  \
    const int off = row * 1024 + ((col * 2) ^ (row << 4));                     \
    *(uint2*)((char*)AH + off) = make_uint2(hw0, hw1);                         \
    *(uint2*)((char*)AL + off) = make_uint2(lw0, lw1);                         \
  }

#define X_MFMA()                                                               \
  hh = (f32x4){0.f, 0.f, 0.f, 0.f};                                           \
  lh = (f32x4){0.f, 0.f, 0.f, 0.f};                                           \
  hl = (f32x4){0.f, 0.f, 0.f, 0.f};                                           \
  _Pragma("unroll") for (int ksl = 0; ksl < 8; ++ksl) {                        \
    const int off = ((kh * 8 + ksl) * 64 + achk) ^ axr;                        \
    short8 ah = *(const short8*)(rowH + off);                                  \
    short8 al = *(const short8*)(rowL + off);                                  \
    hh = __builtin_amdgcn_mfma_f32_16x16x32_bf16(ah, bxh[ksl], hh, 0, 0, 0);   \
    lh = __builtin_amdgcn_mfma_f32_16x16x32_bf16(al, bxh[ksl], lh, 0, 0, 0);   \
    hl = __builtin_amdgcn_mfma_f32_16x16x32_bf16(ah, bxl[ksl], hl, 0, 0, 0);   \
  }

__global__ __launch_bounds__(NTHR, 2) void lstm_r4(
    const float* __restrict__ x, const int* __restrict__ len,
    const float* __restrict__ bias, const uint32_t* __restrict__ fragWx,
    const uint32_t* __restrict__ fragWh, uint32_t* __restrict__ h_pair,
    float* __restrict__ out) {
  const int tid = threadIdx.x;
  const int lane = tid & 63;
  const int wave = tid >> 6;
  const int gp = wave >> 1;
  const int kh = wave & 1;
  const int group = blockIdx.x & 7;
  const int jblk = blockIdx.x >> 3;
  const int b0 = group * GR4;
  const int j0 = jblk << 4;
  uint32_t* hbase = h_pair + (size_t)group * 2 * (GR4 * HH);

  __shared__ uint16_t AH[GR4 * 512];
  __shared__ uint16_t AL[GR4 * 512];
  __shared__ float ex[8][GR4][16];
  __shared__ float c_st[GR4][16];
  __shared__ float h_st[GR4][16];
  __shared__ float bias_l[4][16];
  __shared__ int len_l[GR4];

  if (tid < GR4 * 16) {
    c_st[tid >> 4][tid & 15] = 0.0f;
    h_st[tid >> 4][tid & 15] = 0.0f;
  }
  if (tid < 64) bias_l[tid >> 4][tid & 15] = bias[(size_t)(tid >> 4) * HH + j0 + (tid & 15)];
  if (tid < GR4) len_l[tid] = len[b0 + tid];

  short8 bxh[8], bxl[8], bhh[8], bhl[8];
  {
    const int nblk = gp * 32 + jblk;
#pragma unroll
    for (int ksl = 0; ksl < 8; ++ksl) {
      const size_t idx = ((size_t)(nblk * 16 + kh * 8 + ksl) * 64 + lane) * 8;
      bxh[ksl] = __builtin_bit_cast(short8, *(const uint4*)(fragWx + idx));
      bxl[ksl] = __builtin_bit_cast(short8, *(const uint4*)(fragWx + idx + 4));
      bhh[ksl] = __builtin_bit_cast(short8, *(const uint4*)(fragWh + idx));
      bhl[ksl] = __builtin_bit_cast(short8, *(const uint4*)(fragWh + idx + 4));
    }
  }

  const int arow = lane & 7;
  const int achk = (lane >> 4) << 4;
  const int axr = arow << 4;
  const char* rowH = (const char*)AH + arow * 1024;
  const char* rowL = (const char*)AL + arow * 1024;

  f32x4 hh = {0.f, 0.f, 0.f, 0.f}, lh = {0.f, 0.f, 0.f, 0.f}, hl = {0.f, 0.f, 0.f, 0.f};
  float4 xp[2];

  LOAD_XP(0);
  __syncthreads();
  STAGE_XP();
  __syncthreads();
  X_MFMA();
  LOAD_XP(1);

  for (int t = 0; t < TT; ++t) {
    const int rbuf = t & 1;
    const int wbuf = rbuf ^ 1;

    if (t > 0) {
      const uint32_t tagp = (((uint32_t)(t - 1)) >> 1) & 3u;
      const uint32_t EXd = ((tagp & 1u) << 14) | ((tagp >> 1) << 30);
      const uint64_t EX2 = ((uint64_t)EXd << 32) | EXd;
      const uint64_t MK2 = 0x4000400040004000ull;
      const unsigned long long* pb =
          (const unsigned long long*)(hbase + (size_t)rbuf * (GR4 * HH)) +
          (size_t)tid * 4;
      uint64_t w0, w1, w2, w3;
      for (;;) {
        w0 = __hip_atomic_load(pb + 0, __ATOMIC_RELAXED, __HIP_MEMORY_SCOPE_AGENT);
        w1 = __hip_atomic_load(pb + 1, __ATOMIC_RELAXED, __HIP_MEMORY_SCOPE_AGENT);
        w2 = __hip_atomic_load(pb + 2, __ATOMIC_RELAXED, __HIP_MEMORY_SCOPE_AGENT);
        w3 = __hip_atomic_load(pb + 3, __ATOMIC_RELAXED, __HIP_MEMORY_SCOPE_AGENT);
        const uint64_t bad =
            (((w0 ^ EX2) | (w1 ^ EX2) | (w2 ^ EX2) | (w3 ^ EX2)) & MK2);
        if (bad == 0ull) break;
      }
      __syncthreads();

      {
        const uint32_t CM = ~0x40004000u;
        uint32_t d0 = (uint32_t)w0 & CM, d1 = (uint32_t)(w0 >> 32) & CM;
        uint32_t d2 = (uint32_t)w1 & CM, d3 = (uint32_t)(w1 >> 32) & CM;
        uint32_t d4 = (uint32_t)w2 & CM, d5 = (uint32_t)(w2 >> 32) & CM;
        uint32_t d6 = (uint32_t)w3 & CM, d7 = (uint32_t)(w3 >> 32) & CM;
        const uint32_t hi0 = (d0 & 0xFFFFu) | (d1 << 16);
        const uint32_t lo0 = (d0 >> 16) | (d1 & 0xFFFF0000u);
        const uint32_t hi1 = (d2 & 0xFFFFu) | (d3 << 16);
        const uint32_t lo1 = (d2 >> 16) | (d3 & 0xFFFF0000u);
        const uint32_t hi2 = (d4 & 0xFFFFu) | (d5 << 16);
        const uint32_t lo2 = (d4 >> 16) | (d5 & 0xFFFF0000u);
        const uint32_t hi3 = (d6 & 0xFFFFu) | (d7 << 16);
        const uint32_t lo3 = (d6 >> 16) | (d7 & 0xFFFF0000u);
        const int woff = wave * 1024 + ((lane * 16) ^ (wave << 4));
        *(uint4*)((char*)AH + woff) = make_uint4(hi0, hi1, hi2, hi3);
        *(uint4*)((char*)AL + woff) = make_uint4(lo0, lo1, lo2, lo3);
      }
      __syncthreads();

#pragma unroll
      for (int ksl = 0; ksl < 8; ++ksl) {
        const int off = ((kh * 8 + ksl) * 64 + achk) ^ axr;
        short8 ah = *(const short8*)(rowH + off);
        short8 al = *(const short8*)(rowL + off);
        hh = __builtin_amdgcn_mfma_f32_16x16x32_bf16(ah, bhh[ksl], hh, 0, 0, 0);
        lh = __builtin_amdgcn_mfma_f32_16x16x32_bf16(al, bhh[ksl], lh, 0, 0, 0);
        hl = __builtin_amdgcn_mfma_f32_16x16x32_bf16(ah, bhl[ksl], hl, 0, 0, 0);
      }
    }

    {
      const int crow = (lane >> 4) << 2;
      const int ccol = lane & 15;
      if (crow < GR4) {
#pragma unroll
        for (int r = 0; r < 4; ++r) ex[wave][crow + r][ccol] = hh[r] + lh[r] + hl[r];
      }
    }
    __syncthreads();

    if (tid < GR4 * 16) {
      const int brow = tid >> 4;
      const int jc = tid & 15;
      const float p0 = ex[0][brow][jc] + ex[1][brow][jc] + bias_l[0][jc];
      const float p1 = ex[2][brow][jc] + ex[3][brow][jc] + bias_l[1][jc];
      const float p2 = ex[4][brow][jc] + ex[5][brow][jc] + bias_l[2][jc];
      const float p3 = ex[6][brow][jc] + ex[7][brow][jc] + bias_l[3][jc];
      const float ig = sigf(p0);
      const float fg = sigf(p1);
      const float cc = tanh_(p2);
      const float og = sigf(p3);
      const float co = c_st[brow][jc];
      const float ct = fg * co + ig * cc;
      const float ht = og * tanh_(ct);
      const bool m = (t < len_l[brow]);
      const float cn = m ? ct : co;
      const float hn = m ? ht : h_st[brow][jc];
      c_st[brow][jc] = cn;
      h_st[brow][jc] = hn;
      out[((size_t)t * BB + b0 + brow) * HH + j0 + jc] = m ? ht : 0.0f;
      uint16_t ph, pl;
      split2(hn, ph, pl);
      const uint32_t tagw = (((uint32_t)t) >> 1) & 3u;
      const uint32_t TB = ((tagw & 1u) << 14) | ((tagw >> 1) << 30);
      const uint32_t hv = ((uint32_t)ph | ((uint32_t)pl << 16)) | TB;
      __hip_atomic_store(hbase + (size_t)wbuf * (GR4 * HH) + brow * HH + j0 + jc,
                         hv, __ATOMIC_RELAXED, __HIP_MEMORY_SCOPE_AGENT);
    }

    if (t + 1 < TT) {
      STAGE_XP();
      __syncthreads();
      X_MFMA();
      LOAD_XP(min(t + 2, TT - 1));
    }
  }
}
#undef LOAD_XP
#undef STAGE_XP
#undef X_MFMA

extern "C" void kernel_launch(void* const* d_in, const int* in_sizes, int n_in,
                              void* d_out, int out_size, void* d_ws, size_t ws_size,
                              hipStream_t stream) {
  const float* x = (const float*)d_in[0];
  const int* len = (const int*)d_in[1];
  const float* Wx = (const float*)d_in[2];    // [2048][512]
  const float* Wh = (const float*)d_in[3];    // [2048][512]
  const float* bias = (const float*)d_in[4];  // [2048]
  float* out = (float*)d_out;

  const size_t FRAG_DW = (size_t)128 * 16 * 64 * 8;   // 4 MB each
  const size_t HP_DW = 65536;                          // 256 KB (both layouts)
  const size_t XA_DW = (size_t)NPAIR * 4 * 1024;       // 2 MB ring
  uint32_t* fragWx = (uint32_t*)d_ws;
  uint32_t* fragWh = fragWx + FRAG_DW;
  uint32_t* h_pair = fragWh + FRAG_DW;
  uint32_t* xaccp = h_pair + HP_DW;
  uint32_t* cnts = xaccp + XA_DW;
  const size_t need = (2 * FRAG_DW + HP_DW + XA_DW + 128) * 4;

  hipMemsetAsync(h_pair, 0xFF, HP_DW * 4, stream);   // tag 3: never matches first uses

  build_frags<<<dim3(512), dim3(256), 0, stream>>>(Wx, fragWx);
  build_frags<<<dim3(512), dim3(256), 0, stream>>>(Wh, fragWh);

  if (ws_size >= need) {
    hipMemsetAsync(xaccp, 0xFF, XA_DW * 4, stream);
    hipMemsetAsync(cnts, 0, 512, stream);
    void* args[] = {(void*)&x,      (void*)&len,    (void*)&bias,  (void*)&fragWx,
                    (void*)&fragWh, (void*)&h_pair, (void*)&xaccp, (void*)&cnts,
                    (void*)&out};
    hipLaunchCooperativeKernel((void*)lstm3, dim3(NWG), dim3(NTHR), args, 0, stream);
  } else {
    void* args[] = {(void*)&x,      (void*)&len,    (void*)&bias, (void*)&fragWx,
                    (void*)&fragWh, (void*)&h_pair, (void*)&out};
    hipLaunchCooperativeKernel((void*)lstm_r4, dim3(NWG4), dim3(NTHR), args, 0, stream);
  }
}

// Round 8
// 3011.744 us; speedup vs baseline: 1.0649x; 1.0649x over previous
//
#include <hip/hip_runtime.h>
#include <stdint.h>

// LSTM (packed sequence) on MI355X — round 8.
// T=512, B=64, D=512, H=512. out[t,b,:] = masked h_t.
//
// 128 WGs = 4 groups (16 batch rows, M=16 fully used) x 32 jblk.
// WAVE SPECIALIZATION inside each WG:
//   waves 0-3 (h-team): poll tagged h_{t-1} from LLC (R4-proven transport:
//     bit14/bit30 of each packed (hi,lo) bf16 dword = 2-bit step tag;
//     |h|<=1 makes those bits provably 0; parity double-buffer; 0xFF init
//     = tag 3 never matches) -> unpack to LDS -> team-bar -> h-MFMA -> ex_h.
//   waves 4-7 (x-team): stage x(t+1) from prefetch regs -> team-bar ->
//     x-MFMA -> ex_x (+bias), CONCURRENT with h-team's poll: the x pipeline
//     hides under the ~1000cy LLC detect latency.
//   One __syncthreads per step; cell (h-team, 256 thr) computes gates,
//   writes out, fire-and-forget tagged h store. ex_x 3-buffered, ex_h
//   2-buffered (no reuse races). Team-local sync = generation-counted LDS
//   atomic barrier (release/acquire), uniform call counts -> no deadlock.
// bf16 3-split MFMA (hi/lo) both GEMMs: absmax ~3.9e-3 (proven R1-R7).

#define TT 512
#define BB 64
#define DD 512
#define HH 512
#define NWG 128
#define NTHR 512
#define GR 16

typedef short short8 __attribute__((ext_vector_type(8)));
typedef float f32x4 __attribute__((ext_vector_type(4)));

__device__ __forceinline__ uint16_t bf16_rne(float f) {
  uint32_t u = __float_as_uint(f);
  u += 0x7fffu + ((u >> 16) & 1u);
  return (uint16_t)(u >> 16);
}

__device__ __forceinline__ void split2(float f, uint16_t &hi, uint16_t &lo) {
  uint16_t h = bf16_rne(f);
  hi = h;
  lo = bf16_rne(f - __uint_as_float(((uint32_t)h) << 16));
}

__device__ __forceinline__ float sigf(float v) { return 1.0f / (1.0f + __expf(-v)); }
__device__ __forceinline__ float tanh_(float v) {
  return 1.0f - 2.0f / (__expf(2.0f * v) + 1.0f);
}

// Build MFMA B-fragment buffer from W [2048][512] (row-major, k contiguous).
// B-frag lane layout for mfma_f32_16x16x32_bf16: col = lane&15,
// k = ks*32 + (lane>>4)*8 + j (8 contiguous k per lane).
__global__ void build_frags(const float* __restrict__ W, uint32_t* __restrict__ frag) {
  const int tid = blockIdx.x * 256 + threadIdx.x;   // 0..131071
  const int lane = tid & 63;
  const int ks = (tid >> 6) & 15;
  const int nblk = tid >> 10;                        // 0..127
  const int col = nblk * 16 + (lane & 15);
  const int k0 = ks * 32 + ((lane >> 4) << 3);
  const float* src = W + (size_t)col * 512 + k0;
  float4 a = *(const float4*)(src);
  float4 b = *(const float4*)(src + 4);
  float v[8] = {a.x, a.y, a.z, a.w, b.x, b.y, b.z, b.w};
  uint32_t hw[4], lw[4];
#pragma unroll
  for (int j = 0; j < 4; ++j) {
    uint16_t h0, l0, h1, l1;
    split2(v[2 * j], h0, l0);
    split2(v[2 * j + 1], h1, l1);
    hw[j] = (uint32_t)h0 | ((uint32_t)h1 << 16);
    lw[j] = (uint32_t)l0 | ((uint32_t)l1 << 16);
  }
  uint4* dst = (uint4*)(frag + (size_t)tid * 8);
  dst[0] = make_uint4(hw[0], hw[1], hw[2], hw[3]);
  dst[1] = make_uint4(lw[0], lw[1], lw[2], lw[3]);
}

__global__ __launch_bounds__(NTHR, 2) void lstm4(
    const float* __restrict__ x, const int* __restrict__ len,
    const float* __restrict__ bias, const uint32_t* __restrict__ fragWx,
    const uint32_t* __restrict__ fragWh, uint32_t* __restrict__ h_pair,
    float* __restrict__ out) {
  const int tid = threadIdx.x;
  const int lane = tid & 63;
  const int wave = tid >> 6;      // 0..7
  const bool isH = wave < 4;
  const int gate = wave & 3;      // gate 0..3 (i,f,c,o) within its team
  const int group = blockIdx.x & 3;
  const int jblk = blockIdx.x >> 2;   // 0..31
  const int b0 = group * GR;
  const int j0 = jblk << 4;
  uint32_t* hbase = h_pair + (size_t)group * 2 * (GR * HH);

  __shared__ uint16_t AH[GR * 512];   // 16 KB  h tile (hi)
  __shared__ uint16_t AL[GR * 512];   // 16 KB  h tile (lo)
  __shared__ uint16_t XH[GR * 512];   // 16 KB  x tile (hi)
  __shared__ uint16_t XL[GR * 512];   // 16 KB  x tile (lo)
  __shared__ float ex_x[3][4][GR][16];   // 12 KB, 3-buffered
  __shared__ float ex_h[2][4][GR][16];   // 8 KB, parity-buffered
  __shared__ float c_st[GR][16];
  __shared__ float h_st[GR][16];
  __shared__ float bias_l[4][16];
  __shared__ int len_l[GR];
  __shared__ uint32_t tb[2];          // [0]=h-team bar, [1]=x-team bar

  if (tid == 0) { tb[0] = 0u; tb[1] = 0u; }
  if (tid < 256) {
    c_st[tid >> 4][tid & 15] = 0.0f;
    h_st[tid >> 4][tid & 15] = 0.0f;
  }
  if (tid < 64) bias_l[tid >> 4][tid & 15] = bias[(size_t)(tid >> 4) * HH + j0 + (tid & 15)];
  if (tid < GR) len_l[tid] = len[b0 + tid];

  // Role-dependent persistent weight fragments: gate, full K=512 (16 ksl).
  short8 wfh[16], wfl[16];
  {
    const uint32_t* fw = isH ? fragWh : fragWx;
    const int nblk = gate * 32 + jblk;
#pragma unroll
    for (int ks = 0; ks < 16; ++ks) {
      const size_t idx = ((size_t)(nblk * 16 + ks) * 64 + lane) * 8;
      wfh[ks] = __builtin_bit_cast(short8, *(const uint4*)(fw + idx));
      wfl[ks] = __builtin_bit_cast(short8, *(const uint4*)(fw + idx + 4));
    }
  }

  // A-frag addressing: row = lane&15, 16B chunk = (lane>>4)*16, XOR swizzle.
  const int arow = lane & 15;
  const int achk = (lane >> 4) << 4;
  const int axr = (arow & 7) << 4;

  const uint64_t MK2 = 0x4000400040004000ull;
  const uint32_t CM = ~0x40004000u;

  __syncthreads();   // P0: init + tb ready

  uint32_t btgt = 0;   // generation target for this wave's team barrier
#define TEAM_BAR(IDX)                                                          \
  {                                                                            \
    btgt += 4;                                                                 \
    if (lane == 0)                                                             \
      __hip_atomic_fetch_add(&tb[IDX], 1u, __ATOMIC_ACQ_REL,                   \
                             __HIP_MEMORY_SCOPE_WORKGROUP);                    \
    while (__hip_atomic_load(&tb[IDX], __ATOMIC_ACQUIRE,                       \
                             __HIP_MEMORY_SCOPE_WORKGROUP) < btgt) {}          \
    asm volatile("" ::: "memory");                                             \
  }

  float4 xp[8];   // x prefetch registers (x-team)
#define XLOAD(tt)                                                              \
  {                                                                            \
    const int xid = tid - 256;                                                 \
    _Pragma("unroll") for (int i = 0; i < 8; ++i) {                            \
      const int f4 = i * 1024 + xid * 4;                                       \
      const int row = f4 >> 9;                                                 \
      const int col = f4 & 511;                                                \
      xp[i] = *(const float4*)(x + ((size_t)(tt) * BB + b0 + row) * DD + col); \
    }                                                                          \
  }
#define XSTAGE()                                                               \
  {                                                                            \
    const int xid = tid - 256;                                                 \
    _Pragma("unroll") for (int i = 0; i < 8; ++i) {                            \
      const int f4 = i * 1024 + xid * 4;                                       \
      const int row = f4 >> 9;                                                 \
      const int col = f4 & 511;                                                \
      uint16_t h0, l0, h1, l1, h2, l2, h3, l3;                                 \
      split2(xp[i].x, h0, l0);                                                 \
      split2(xp[i].y, h1, l1);                                                 \
      split2(xp[i].z, h2, l2);                                                 \
      split2(xp[i].w, h3, l3);                                                 \
      const int off = row * 1024 + ((col * 2) ^ ((row & 7) << 4));             \
      *(uint2*)((char*)XH + off) = make_uint2(                                 \
          (uint32_t)h0 | ((uint32_t)h1 << 16), (uint32_t)h2 | ((uint32_t)h3 << 16)); \
      *(uint2*)((char*)XL + off) = make_uint2(                                 \
          (uint32_t)l0 | ((uint32_t)l1 << 16), (uint32_t)l2 | ((uint32_t)l3 << 16)); \
    }                                                                          \
  }
#define XMFMA(BUF)                                                             \
  {                                                                            \
    f32x4 hh = {0.f, 0.f, 0.f, 0.f}, lh = {0.f, 0.f, 0.f, 0.f},               \
          hl = {0.f, 0.f, 0.f, 0.f};                                           \
    const char* rH = (const char*)XH + arow * 1024;                            \
    const char* rL = (const char*)XL + arow * 1024;                            \
    _Pragma("unroll") for (int ks = 0; ks < 16; ++ks) {                        \
      const int off = (ks * 64 + achk) ^ axr;                                  \
      short8 ah = *(const short8*)(rH + off);                                  \
      short8 al = *(const short8*)(rL + off);                                  \
      hh = __builtin_amdgcn_mfma_f32_16x16x32_bf16(ah, wfh[ks], hh, 0, 0, 0);  \
      lh = __builtin_amdgcn_mfma_f32_16x16x32_bf16(al, wfh[ks], lh, 0, 0, 0);  \
      hl = __builtin_amdgcn_mfma_f32_16x16x32_bf16(ah, wfl[ks], hl, 0, 0, 0);  \
    }                                                                          \
    const int crow = (lane >> 4) << 2;                                         \
    const int ccol = lane & 15;                                                \
    _Pragma("unroll") for (int r = 0; r < 4; ++r)                              \
      ex_x[BUF][gate][crow + r][ccol] =                                        \
          hh[r] + lh[r] + hl[r] + bias_l[gate][ccol];                          \
  }

  // ---- x-team prologue: ex_x[0] = proj(x_0); prefetch x_1 ----
  if (!isH) {
    XLOAD(0);
    XSTAGE();
    TEAM_BAR(1);
    XMFMA(0);
    XLOAD(1);
  }

  for (int t = 0; t < TT; ++t) {
    if (isH) {
      if (t > 0) {
        // --- poll tagged h_{t-1}: 16 u64 per thread (row tid>>4) ---
        const int rbuf = t & 1;
        const uint32_t tg = (((uint32_t)(t - 1)) >> 1) & 3u;
        const uint32_t EXd = ((tg & 1u) << 14) | ((tg >> 1) << 30);
        const uint64_t EX2 = ((uint64_t)EXd << 32) | EXd;
        const unsigned long long* pb =
            (const unsigned long long*)(hbase + (size_t)rbuf * (GR * HH)) +
            (tid >> 4) * 256 + (tid & 15) * 16;
        uint64_t w[16];
        for (;;) {
#pragma unroll
          for (int q = 0; q < 16; ++q)
            w[q] = __hip_atomic_load(pb + q, __ATOMIC_RELAXED, __HIP_MEMORY_SCOPE_AGENT);
          uint64_t bad = 0;
#pragma unroll
          for (int q = 0; q < 16; ++q) bad |= (w[q] ^ EX2);
          if ((bad & MK2) == 0ull) break;
        }
        // --- unpack: clear tags, split hi/lo, swizzled LDS writes ---
        {
          const int base = (tid >> 4) * 1024;
          const int swz = ((tid >> 4) & 7) << 4;
          const int cb = (tid & 15) * 64;
#pragma unroll
          for (int c = 0; c < 4; ++c) {
            const uint32_t d0 = (uint32_t)w[4 * c + 0] & CM;
            const uint32_t d1 = (uint32_t)(w[4 * c + 0] >> 32) & CM;
            const uint32_t d2 = (uint32_t)w[4 * c + 1] & CM;
            const uint32_t d3 = (uint32_t)(w[4 * c + 1] >> 32) & CM;
            const uint32_t d4 = (uint32_t)w[4 * c + 2] & CM;
            const uint32_t d5 = (uint32_t)(w[4 * c + 2] >> 32) & CM;
            const uint32_t d6 = (uint32_t)w[4 * c + 3] & CM;
            const uint32_t d7 = (uint32_t)(w[4 * c + 3] >> 32) & CM;
            const int off = base + ((cb + 16 * c) ^ swz);
            *(uint4*)((char*)AH + off) = make_uint4(
                (d0 & 0xFFFFu) | (d1 << 16), (d2 & 0xFFFFu) | (d3 << 16),
                (d4 & 0xFFFFu) | (d5 << 16), (d6 & 0xFFFFu) | (d7 << 16));
            *(uint4*)((char*)AL + off) = make_uint4(
                (d0 >> 16) | (d1 & 0xFFFF0000u), (d2 >> 16) | (d3 & 0xFFFF0000u),
                (d4 >> 16) | (d5 & 0xFFFF0000u), (d6 >> 16) | (d7 & 0xFFFF0000u));
          }
        }
        TEAM_BAR(0);   // h tile visible to all h-waves
        // --- h MFMA: gate `gate`, full K ---
        {
          f32x4 hh = {0.f, 0.f, 0.f, 0.f}, lh = {0.f, 0.f, 0.f, 0.f},
                hl = {0.f, 0.f, 0.f, 0.f};
          const char* rH = (const char*)AH + arow * 1024;
          const char* rL = (const char*)AL + arow * 1024;
#pragma unroll
          for (int ks = 0; ks < 16; ++ks) {
            const int off = (ks * 64 + achk) ^ axr;
            short8 ah = *(const short8*)(rH + off);
            short8 al = *(const short8*)(rL + off);
            hh = __builtin_amdgcn_mfma_f32_16x16x32_bf16(ah, wfh[ks], hh, 0, 0, 0);
            lh = __builtin_amdgcn_mfma_f32_16x16x32_bf16(al, wfh[ks], lh, 0, 0, 0);
            hl = __builtin_amdgcn_mfma_f32_16x16x32_bf16(ah, wfl[ks], hl, 0, 0, 0);
          }
          const int crow = (lane >> 4) << 2;
          const int ccol = lane & 15;
#pragma unroll
          for (int r = 0; r < 4; ++r)
            ex_h[t & 1][gate][crow + r][ccol] = hh[r] + lh[r] + hl[r];
        }
      }
    } else {
      if (t + 1 < TT) {
        XSTAGE();                                   // stage x(t+1) from regs
        XLOAD(t + 2 < TT ? t + 2 : TT - 1);         // prefetch x(t+2)
        TEAM_BAR(1);                                // x tile visible to x-waves
        XMFMA((t + 1) % 3);                         // ex_x for step t+1
      }
    }

    __syncthreads();   // B: ex_h(t) + (ex_x(t) from iter t-1) ready

    if (isH && tid < 256) {
      const int brow = tid >> 4;
      const int jc = tid & 15;
      const int xb = t % 3;
      float p0 = ex_x[xb][0][brow][jc];
      float p1 = ex_x[xb][1][brow][jc];
      float p2 = ex_x[xb][2][brow][jc];
      float p3 = ex_x[xb][3][brow][jc];
      if (t > 0) {
        const int hb = t & 1;
        p0 += ex_h[hb][0][brow][jc];
        p1 += ex_h[hb][1][brow][jc];
        p2 += ex_h[hb][2][brow][jc];
        p3 += ex_h[hb][3][brow][jc];
      }
      const float ig = sigf(p0);
      const float fg = sigf(p1);
      const float cc = tanh_(p2);
      const float og = sigf(p3);
      const float co = c_st[brow][jc];
      const float ct = fg * co + ig * cc;
      const float ht = og * tanh_(ct);
      const bool m = (t < len_l[brow]);
      const float cn = m ? ct : co;
      const float hn = m ? ht : h_st[brow][jc];
      c_st[brow][jc] = cn;
      h_st[brow][jc] = hn;
      out[((size_t)t * BB + b0 + brow) * HH + j0 + jc] = m ? ht : 0.0f;
      uint16_t ph, pl;
      split2(hn, ph, pl);   // |hn| <= 1 -> bit14 of both halves = 0
      const uint32_t tagw = (((uint32_t)t) >> 1) & 3u;
      const uint32_t TB = ((tagw & 1u) << 14) | ((tagw >> 1) << 30);
      __hip_atomic_store(hbase + (size_t)((t + 1) & 1) * (GR * HH) + brow * HH + j0 + jc,
                         ((uint32_t)ph | ((uint32_t)pl << 16)) | TB,
                         __ATOMIC_RELAXED, __HIP_MEMORY_SCOPE_AGENT);
    }
  }
#undef TEAM_BAR
#undef XLOAD
#undef XSTAGE
#undef XMFMA
}

extern "C" void kernel_launch(void* const* d_in, const int* in_sizes, int n_in,
                              void* d_out, int out_size, void* d_ws, size_t ws_size,
                              hipStream_t stream) {
  const float* x = (const float*)d_in[0];
  const int* len = (const int*)d_in[1];
  const float* Wx = (const float*)d_in[2];    // [2048][512]
  const float* Wh = (const float*)d_in[3];    // [2048][512]
  const float* bias = (const float*)d_in[4];  // [2048]
  float* out = (float*)d_out;

  const size_t FRAG_DW = (size_t)128 * 16 * 64 * 8;   // 4 MB each
  const size_t HP_DW = (size_t)4 * 2 * GR * HH;        // 256 KB
  uint32_t* fragWx = (uint32_t*)d_ws;
  uint32_t* fragWh = fragWx + FRAG_DW;
  uint32_t* h_pair = fragWh + FRAG_DW;
  // total need ~8.5 MB; ws proven >= 10.75 MB (R7's lstm3 ran).

  // 0xFF -> tag bits = 3 in every dword: never matches the first expected
  // tags and is overwritten >=2x before tag 3 recurs.
  hipMemsetAsync(h_pair, 0xFF, HP_DW * 4, stream);

  build_frags<<<dim3(512), dim3(256), 0, stream>>>(Wx, fragWx);
  build_frags<<<dim3(512), dim3(256), 0, stream>>>(Wh, fragWh);

  void* args[] = {(void*)&x,      (void*)&len,    (void*)&bias, (void*)&fragWx,
                  (void*)&fragWh, (void*)&h_pair, (void*)&out};
  hipLaunchCooperativeKernel((void*)lstm4, dim3(NWG), dim3(NTHR), args, 0, stream);
}

// Round 9
// 1971.667 us; speedup vs baseline: 1.6267x; 1.5275x over previous
//
#include <hip/hip_runtime.h>
#include <stdint.h>

// LSTM (packed sequence) on MI355X — round 9.
// T=512, B=64, D=512, H=512. out[t,b,:] = masked h_t.
//
// R4 structure (best so far), two changes aimed at LLC poll pressure:
//   1) GR=16: 128 WGs = 4 groups (16 batch rows, MFMA M fully used) x 32
//      jblk. Halves the number of polling WGs; per-CU MFMA time unchanged.
//   2) TWO-PHASE POLL: each thread polls only its FIRST u64 (8 B/iter,
//      was 32 B); on tag match, loads the remaining 7 once and re-loads
//      only-stale until all tagged. Chip poll traffic 4 MB -> 0.5 MB/iter.
// Transport unchanged (proven R4/R6): SELF-DESCRIBING TAGGED DATA at LLC —
// bit14/bit30 of each packed (hi,lo) bf16 dword carry a 2-bit step tag
// (|h|<=1 makes those bits provably 0); parity double-buffer; 0xFF init =
// tag 3 never matches first uses. Poll->sync->store ordering makes buffer
// overwrite provably safe (producers == consumers per group).
// bf16 3-split MFMA (hi/lo) both GEMMs: absmax ~3.9e-3 (proven R1-R8).

#define TT 512
#define BB 64
#define DD 512
#define HH 512
#define NWG 128
#define NTHR 512
#define GR 16

typedef short short8 __attribute__((ext_vector_type(8)));
typedef float f32x4 __attribute__((ext_vector_type(4)));

__device__ __forceinline__ uint16_t bf16_rne(float f) {
  uint32_t u = __float_as_uint(f);
  u += 0x7fffu + ((u >> 16) & 1u);
  return (uint16_t)(u >> 16);
}

__device__ __forceinline__ void split2(float f, uint16_t &hi, uint16_t &lo) {
  uint16_t h = bf16_rne(f);
  hi = h;
  lo = bf16_rne(f - __uint_as_float(((uint32_t)h) << 16));
}

__device__ __forceinline__ float sigf(float v) { return 1.0f / (1.0f + __expf(-v)); }
__device__ __forceinline__ float tanh_(float v) {
  return 1.0f - 2.0f / (__expf(2.0f * v) + 1.0f);
}

// Build MFMA B-fragment buffer from W [2048][512] (row-major, k contiguous).
// B-frag lane layout for mfma_f32_16x16x32_bf16: col = lane&15,
// k = ks*32 + (lane>>4)*8 + j (8 contiguous k per lane).
__global__ void build_frags(const float* __restrict__ W, uint32_t* __restrict__ frag) {
  const int tid = blockIdx.x * 256 + threadIdx.x;   // 0..131071
  const int lane = tid & 63;
  const int ks = (tid >> 6) & 15;
  const int nblk = tid >> 10;                        // 0..127
  const int col = nblk * 16 + (lane & 15);
  const int k0 = ks * 32 + ((lane >> 4) << 3);
  const float* src = W + (size_t)col * 512 + k0;
  float4 a = *(const float4*)(src);
  float4 b = *(const float4*)(src + 4);
  float v[8] = {a.x, a.y, a.z, a.w, b.x, b.y, b.z, b.w};
  uint32_t hw[4], lw[4];
#pragma unroll
  for (int j = 0; j < 4; ++j) {
    uint16_t h0, l0, h1, l1;
    split2(v[2 * j], h0, l0);
    split2(v[2 * j + 1], h1, l1);
    hw[j] = (uint32_t)h0 | ((uint32_t)h1 << 16);
    lw[j] = (uint32_t)l0 | ((uint32_t)l1 << 16);
  }
  uint4* dst = (uint4*)(frag + (size_t)tid * 8);
  dst[0] = make_uint4(hw[0], hw[1], hw[2], hw[3]);
  dst[1] = make_uint4(lw[0], lw[1], lw[2], lw[3]);
}

__global__ __launch_bounds__(NTHR, 2) void lstm5(
    const float* __restrict__ x, const int* __restrict__ len,
    const float* __restrict__ bias, const uint32_t* __restrict__ fragWx,
    const uint32_t* __restrict__ fragWh, uint32_t* __restrict__ h_pair,
    float* __restrict__ out) {
  const int tid = threadIdx.x;
  const int lane = tid & 63;
  const int wave = tid >> 6;      // 0..7
  const int gp = wave >> 1;       // gate 0..3 (i,f,c,o)
  const int kh = wave & 1;        // K half
  const int group = blockIdx.x & 3;
  const int jblk = blockIdx.x >> 2;   // 0..31
  const int b0 = group * GR;
  const int j0 = jblk << 4;
  uint32_t* hbase = h_pair + (size_t)group * 2 * (GR * HH);

  __shared__ uint16_t AH[GR * 512];   // 16 KB
  __shared__ uint16_t AL[GR * 512];   // 16 KB
  __shared__ float ex[8][GR][16];     // 8 KB
  __shared__ float c_st[GR][16];
  __shared__ float h_st[GR][16];
  __shared__ float bias_l[4][16];
  __shared__ int len_l[GR];

  if (tid < GR * 16) {
    c_st[tid >> 4][tid & 15] = 0.0f;
    h_st[tid >> 4][tid & 15] = 0.0f;
  }
  if (tid < 64) bias_l[tid >> 4][tid & 15] = bias[(size_t)(tid >> 4) * HH + j0 + (tid & 15)];
  if (tid < GR) len_l[tid] = len[b0 + tid];

  // Persistent B fragments: this wave's gate, this jblk, its K half.
  short8 bxh[8], bxl[8], bhh[8], bhl[8];
  {
    const int nblk = gp * 32 + jblk;
#pragma unroll
    for (int ksl = 0; ksl < 8; ++ksl) {
      const size_t idx = ((size_t)(nblk * 16 + kh * 8 + ksl) * 64 + lane) * 8;
      bxh[ksl] = __builtin_bit_cast(short8, *(const uint4*)(fragWx + idx));
      bxl[ksl] = __builtin_bit_cast(short8, *(const uint4*)(fragWx + idx + 4));
      bhh[ksl] = __builtin_bit_cast(short8, *(const uint4*)(fragWh + idx));
      bhl[ksl] = __builtin_bit_cast(short8, *(const uint4*)(fragWh + idx + 4));
    }
  }

  // A-frag addressing: row = lane&15 (all 16 real), 16B chunk = (lane>>4)*16,
  // XOR swizzle (row&7)<<4 (matches the unpack/stage writes below).
  const int arow = lane & 15;
  const int achk = (lane >> 4) << 4;
  const int axr = (arow & 7) << 4;
  const char* rowH = (const char*)AH + arow * 1024;
  const char* rowL = (const char*)AL + arow * 1024;

  f32x4 hh = {0.f, 0.f, 0.f, 0.f}, lh = {0.f, 0.f, 0.f, 0.f}, hl = {0.f, 0.f, 0.f, 0.f};
  float4 xp[4];

  const uint64_t MK2 = 0x4000400040004000ull;
  const uint32_t CM = ~0x40004000u;

#define LOAD_XP(tt)                                                            \
  _Pragma("unroll") for (int i = 0; i < 4; ++i) {                              \
    const int flat4 = i * 2048 + tid * 4;                                      \
    const int row = flat4 >> 9;                                                \
    const int col = flat4 & 511;                                               \
    xp[i] = *(const float4*)(x + ((size_t)(tt) * BB + b0 + row) * DD + col);   \
  }

#define STAGE_XP()                                                             \
  _Pragma("unroll") for (int i = 0; i < 4; ++i) {                              \
    const int flat4 = i * 2048 + tid * 4;                                      \
    const int row = flat4 >> 9;                                                \
    const int col = flat4 & 511;                                               \
    uint16_t h0, l0, h1, l1, h2, l2, h3, l3;                                   \
    split2(xp[i].x, h0, l0);                                                   \
    split2(xp[i].y, h1, l1);                                                   \
    split2(xp[i].z, h2, l2);                                                   \
    split2(xp[i].w, h3, l3);                                                   \
    const uint32_t hw0 = (uint32_t)h0 | ((uint32_t)h1 << 16);                  \
    const uint32_t hw1 = (uint32_t)h2 | ((uint32_t)h3 << 16);                  \
    const uint32_t lw0 = (uint32_t)l0 | ((uint32_t)l1 << 16);                  \
    const uint32_t lw1 = (uint32_t)l2 | ((uint32_t)l3 << 16);                  \
    const int off = row * 1024 + ((col * 2) ^ ((row & 7) << 4));               \
    *(uint2*)((char*)AH + off) = make_uint2(hw0, hw1);                         \
    *(uint2*)((char*)AL + off) = make_uint2(lw0, lw1);                         \
  }

#define X_MFMA()                                                               \
  hh = (f32x4){0.f, 0.f, 0.f, 0.f};                                           \
  lh = (f32x4){0.f, 0.f, 0.f, 0.f};                                           \
  hl = (f32x4){0.f, 0.f, 0.f, 0.f};                                           \
  _Pragma("unroll") for (int ksl = 0; ksl < 8; ++ksl) {                        \
    const int off = ((kh * 8 + ksl) * 64 + achk) ^ axr;                        \
    short8 ah = *(const short8*)(rowH + off);                                  \
    short8 al = *(const short8*)(rowL + off);                                  \
    hh = __builtin_amdgcn_mfma_f32_16x16x32_bf16(ah, bxh[ksl], hh, 0, 0, 0);   \
    lh = __builtin_amdgcn_mfma_f32_16x16x32_bf16(al, bxh[ksl], lh, 0, 0, 0);   \
    hl = __builtin_amdgcn_mfma_f32_16x16x32_bf16(ah, bxl[ksl], hl, 0, 0, 0);   \
  }

  // ---- prologue: xacc for t=0, prefetch x_1 ----
  LOAD_XP(0);
  __syncthreads();
  STAGE_XP();
  __syncthreads();
  X_MFMA();
  LOAD_XP(1);

  for (int t = 0; t < TT; ++t) {
    const int rbuf = t & 1;
    const int wbuf = rbuf ^ 1;

    if (t > 0) {
      // --- two-phase poll of tagged h_{t-1}: thread owns 8 u64 (64 B) ---
      const uint32_t tg = (((uint32_t)(t - 1)) >> 1) & 3u;
      const uint32_t Ed = ((tg & 1u) << 14) | ((tg >> 1) << 30);
      const uint64_t EX2 = ((uint64_t)Ed << 32) | Ed;
      const unsigned long long* pb =
          (const unsigned long long*)(hbase + (size_t)rbuf * (GR * HH)) +
          (size_t)tid * 8;
      uint64_t w[8];
      // phase 1: spin on the sentinel u64 only (8 B per iteration)
      do {
        w[0] = __hip_atomic_load(pb, __ATOMIC_RELAXED, __HIP_MEMORY_SCOPE_AGENT);
      } while ((w[0] ^ EX2) & MK2);
      // phase 2: fetch the rest once; re-fetch all while any stale (rare)
#pragma unroll
      for (int q = 1; q < 8; ++q)
        w[q] = __hip_atomic_load(pb + q, __ATOMIC_RELAXED, __HIP_MEMORY_SCOPE_AGENT);
      for (;;) {
        uint64_t bad = 0;
#pragma unroll
        for (int q = 1; q < 8; ++q) bad |= (w[q] ^ EX2);
        if ((bad & MK2) == 0ull) break;
#pragma unroll
        for (int q = 1; q < 8; ++q)
          w[q] = __hip_atomic_load(pb + q, __ATOMIC_RELAXED, __HIP_MEMORY_SCOPE_AGENT);
      }
      __syncthreads();   // all threads have their data; prev tail X_MFMA done

      // --- clear tags, pack hi/lo, swizzled LDS writes (16 dwords) ---
      {
        uint32_t d[16];
#pragma unroll
        for (int q = 0; q < 8; ++q) {
          d[2 * q] = (uint32_t)w[q] & CM;
          d[2 * q + 1] = (uint32_t)(w[q] >> 32) & CM;
        }
        uint32_t hw[8], lw[8];
#pragma unroll
        for (int j = 0; j < 8; ++j) {
          hw[j] = (d[2 * j] & 0xFFFFu) | (d[2 * j + 1] << 16);
          lw[j] = (d[2 * j] >> 16) | (d[2 * j + 1] & 0xFFFF0000u);
        }
        const int rrow = tid >> 5;          // 32 threads per 512-elem row
        const int base = rrow * 1024;
        const int swz = (rrow & 7) << 4;
        const int cb = (tid & 31) * 32;     // byte col of first 16B chunk
        *(uint4*)((char*)AH + base + (cb ^ swz)) = make_uint4(hw[0], hw[1], hw[2], hw[3]);
        *(uint4*)((char*)AH + base + ((cb + 16) ^ swz)) = make_uint4(hw[4], hw[5], hw[6], hw[7]);
        *(uint4*)((char*)AL + base + (cb ^ swz)) = make_uint4(lw[0], lw[1], lw[2], lw[3]);
        *(uint4*)((char*)AL + base + ((cb + 16) ^ swz)) = make_uint4(lw[4], lw[5], lw[6], lw[7]);
      }
      __syncthreads();

      // --- h MFMA (accumulates onto x-projection from prev tail) ---
#pragma unroll
      for (int ksl = 0; ksl < 8; ++ksl) {
        const int off = ((kh * 8 + ksl) * 64 + achk) ^ axr;
        short8 ah = *(const short8*)(rowH + off);
        short8 al = *(const short8*)(rowL + off);
        hh = __builtin_amdgcn_mfma_f32_16x16x32_bf16(ah, bhh[ksl], hh, 0, 0, 0);
        lh = __builtin_amdgcn_mfma_f32_16x16x32_bf16(al, bhh[ksl], lh, 0, 0, 0);
        hl = __builtin_amdgcn_mfma_f32_16x16x32_bf16(ah, bhl[ksl], hl, 0, 0, 0);
      }
    }

    // --- exchange partial preacts (all 16 C rows real) ---
    {
      const int crow = (lane >> 4) << 2;
      const int ccol = lane & 15;
#pragma unroll
      for (int r = 0; r < 4; ++r) ex[wave][crow + r][ccol] = hh[r] + lh[r] + hl[r];
    }
    __syncthreads();   // S1: ex ready; tile free

    // --- cell update (16x16 = 256 threads); tagged h store ---
    if (tid < 256) {
      const int brow = tid >> 4;
      const int jc = tid & 15;
      const float p0 = ex[0][brow][jc] + ex[1][brow][jc] + bias_l[0][jc];
      const float p1 = ex[2][brow][jc] + ex[3][brow][jc] + bias_l[1][jc];
      const float p2 = ex[4][brow][jc] + ex[5][brow][jc] + bias_l[2][jc];
      const float p3 = ex[6][brow][jc] + ex[7][brow][jc] + bias_l[3][jc];
      const float ig = sigf(p0);
      const float fg = sigf(p1);
      const float cc = tanh_(p2);
      const float og = sigf(p3);
      const float co = c_st[brow][jc];
      const float ct = fg * co + ig * cc;
      const float ht = og * tanh_(ct);
      const bool m = (t < len_l[brow]);
      const float cn = m ? ct : co;
      const float hn = m ? ht : h_st[brow][jc];
      c_st[brow][jc] = cn;
      h_st[brow][jc] = hn;
      out[((size_t)t * BB + b0 + brow) * HH + j0 + jc] = m ? ht : 0.0f;
      uint16_t ph, pl;
      split2(hn, ph, pl);   // |hn| <= 1 -> bit14 of both halves = 0
      const uint32_t tagw = (((uint32_t)t) >> 1) & 3u;
      const uint32_t TB = ((tagw & 1u) << 14) | ((tagw >> 1) << 30);
      __hip_atomic_store(hbase + (size_t)wbuf * (GR * HH) + brow * HH + j0 + jc,
                         ((uint32_t)ph | ((uint32_t)pl << 16)) | TB,
                         __ATOMIC_RELAXED, __HIP_MEMORY_SCOPE_AGENT);
    }

    if (t + 1 < TT) {
      STAGE_XP();        // stage x_{t+1}
      __syncthreads();   // S2
      X_MFMA();          // xacc for t+1 — off the serial h path
      LOAD_XP(min(t + 2, TT - 1));
    }
  }
#undef LOAD_XP
#undef STAGE_XP
#undef X_MFMA
}

extern "C" void kernel_launch(void* const* d_in, const int* in_sizes, int n_in,
                              void* d_out, int out_size, void* d_ws, size_t ws_size,
                              hipStream_t stream) {
  const float* x = (const float*)d_in[0];
  const int* len = (const int*)d_in[1];
  const float* Wx = (const float*)d_in[2];    // [2048][512]
  const float* Wh = (const float*)d_in[3];    // [2048][512]
  const float* bias = (const float*)d_in[4];  // [2048]
  float* out = (float*)d_out;

  const size_t FRAG_DW = (size_t)128 * 16 * 64 * 8;   // 4 MB each
  const size_t HP_DW = (size_t)4 * 2 * GR * HH;        // 256 KB
  uint32_t* fragWx = (uint32_t*)d_ws;
  uint32_t* fragWh = fragWx + FRAG_DW;
  uint32_t* h_pair = fragWh + FRAG_DW;
  // total ~8.5 MB; ws proven >= 10.75 MB (R7's lstm3 ran).

  // 0xFF -> tag bits = 3 in every dword: never matches the first expected
  // tags and is overwritten >=2x before tag 3 recurs.
  hipMemsetAsync(h_pair, 0xFF, HP_DW * 4, stream);

  build_frags<<<dim3(512), dim3(256), 0, stream>>>(Wx, fragWx);
  build_frags<<<dim3(512), dim3(256), 0, stream>>>(Wh, fragWh);

  void* args[] = {(void*)&x,      (void*)&len,    (void*)&bias, (void*)&fragWx,
                  (void*)&fragWh, (void*)&h_pair, (void*)&out};
  hipLaunchCooperativeKernel((void*)lstm5, dim3(NWG), dim3(NTHR), args, 0, stream);
}

// Round 10
// 1436.122 us; speedup vs baseline: 2.2333x; 1.3729x over previous
//
#include <hip/hip_runtime.h>
#include <stdint.h>

// LSTM (packed sequence) on MI355X — round 10.
// T=512, B=64, D=512, H=512. out[t,b,:] = masked h_t.
//
// R4 structure (best: 256 WGs = 8 groups x 32 jblk, GR=8, 2 WGs/CU TLP,
// flat 4-u64 tagged poll) with two serial-chain reductions:
//   1) Double-buffered h-tile (parity) + SEPARATE x-tile: head becomes
//      poll -> unpack directly into H[t&1] -> ONE sync -> h-MFMA
//      (was poll -> sync -> unpack -> sync -> MFMA). Unpack moves off the
//      all-threads path; one barrier removed. Safe: H[t&1]'s last reader
//      was the h-MFMA at t-2, four barriers earlier.
//   2) Early h-store: cell computes hn, issues the tagged LLC store BEFORE
//      the out write / LDS state updates (visibility starts sooner).
// Transport unchanged (proven R4-R9): SELF-DESCRIBING TAGGED DATA at LLC —
// bit14/bit30 of each packed (hi,lo) bf16 dword carry a 2-bit step tag
// (|h|<=1 makes those bits provably 0); parity double-buffer; 0xFF init =
// tag 3 never matches first uses.
// bf16 3-split MFMA (hi/lo) both GEMMs: absmax ~3.9e-3 (proven R1-R9).

#define TT 512
#define BB 64
#define DD 512
#define HH 512
#define NWG 256
#define NTHR 512
#define GR 8

typedef short short8 __attribute__((ext_vector_type(8)));
typedef float f32x4 __attribute__((ext_vector_type(4)));

__device__ __forceinline__ uint16_t bf16_rne(float f) {
  uint32_t u = __float_as_uint(f);
  u += 0x7fffu + ((u >> 16) & 1u);
  return (uint16_t)(u >> 16);
}

__device__ __forceinline__ void split2(float f, uint16_t &hi, uint16_t &lo) {
  uint16_t h = bf16_rne(f);
  hi = h;
  lo = bf16_rne(f - __uint_as_float(((uint32_t)h) << 16));
}

__device__ __forceinline__ float sigf(float v) { return 1.0f / (1.0f + __expf(-v)); }
__device__ __forceinline__ float tanh_(float v) {
  return 1.0f - 2.0f / (__expf(2.0f * v) + 1.0f);
}

// Build MFMA B-fragment buffer from W [2048][512] (row-major, k contiguous).
// B-frag lane layout for mfma_f32_16x16x32_bf16: col = lane&15,
// k = ks*32 + (lane>>4)*8 + j (8 contiguous k per lane).
__global__ void build_frags(const float* __restrict__ W, uint32_t* __restrict__ frag) {
  const int tid = blockIdx.x * 256 + threadIdx.x;   // 0..131071
  const int lane = tid & 63;
  const int ks = (tid >> 6) & 15;
  const int nblk = tid >> 10;                        // 0..127
  const int col = nblk * 16 + (lane & 15);
  const int k0 = ks * 32 + ((lane >> 4) << 3);
  const float* src = W + (size_t)col * 512 + k0;
  float4 a = *(const float4*)(src);
  float4 b = *(const float4*)(src + 4);
  float v[8] = {a.x, a.y, a.z, a.w, b.x, b.y, b.z, b.w};
  uint32_t hw[4], lw[4];
#pragma unroll
  for (int j = 0; j < 4; ++j) {
    uint16_t h0, l0, h1, l1;
    split2(v[2 * j], h0, l0);
    split2(v[2 * j + 1], h1, l1);
    hw[j] = (uint32_t)h0 | ((uint32_t)h1 << 16);
    lw[j] = (uint32_t)l0 | ((uint32_t)l1 << 16);
  }
  uint4* dst = (uint4*)(frag + (size_t)tid * 8);
  dst[0] = make_uint4(hw[0], hw[1], hw[2], hw[3]);
  dst[1] = make_uint4(lw[0], lw[1], lw[2], lw[3]);
}

__global__ __launch_bounds__(NTHR, 2) void lstm6(
    const float* __restrict__ x, const int* __restrict__ len,
    const float* __restrict__ bias, const uint32_t* __restrict__ fragWx,
    const uint32_t* __restrict__ fragWh, uint32_t* __restrict__ h_pair,
    float* __restrict__ out) {
  const int tid = threadIdx.x;
  const int lane = tid & 63;
  const int wave = tid >> 6;      // 0..7
  const int gp = wave >> 1;       // gate 0..3 (i,f,c,o)
  const int kh = wave & 1;        // K half
  const int group = blockIdx.x & 7;
  const int jblk = blockIdx.x >> 3;   // 0..31
  const int b0 = group * GR;
  const int j0 = jblk << 4;
  uint32_t* hbase = h_pair + (size_t)group * 2 * (GR * HH);

  __shared__ uint16_t HAH[2][GR * 512];   // 16 KB  h tile hi, parity dbuf
  __shared__ uint16_t HAL[2][GR * 512];   // 16 KB  h tile lo
  __shared__ uint16_t XH[GR * 512];       // 8 KB   x tile hi
  __shared__ uint16_t XL[GR * 512];       // 8 KB   x tile lo
  __shared__ float ex[8][GR][16];         // 4 KB
  __shared__ float c_st[GR][16];
  __shared__ float h_st[GR][16];
  __shared__ float bias_l[4][16];
  __shared__ int len_l[GR];

  if (tid < GR * 16) {
    c_st[tid >> 4][tid & 15] = 0.0f;
    h_st[tid >> 4][tid & 15] = 0.0f;
  }
  if (tid < 64) bias_l[tid >> 4][tid & 15] = bias[(size_t)(tid >> 4) * HH + j0 + (tid & 15)];
  if (tid < GR) len_l[tid] = len[b0 + tid];

  // Persistent B fragments: this wave's gate, this jblk, its K half.
  short8 bxh[8], bxl[8], bhh[8], bhl[8];
  {
    const int nblk = gp * 32 + jblk;
#pragma unroll
    for (int ksl = 0; ksl < 8; ++ksl) {
      const size_t idx = ((size_t)(nblk * 16 + kh * 8 + ksl) * 64 + lane) * 8;
      bxh[ksl] = __builtin_bit_cast(short8, *(const uint4*)(fragWx + idx));
      bxl[ksl] = __builtin_bit_cast(short8, *(const uint4*)(fragWx + idx + 4));
      bhh[ksl] = __builtin_bit_cast(short8, *(const uint4*)(fragWh + idx));
      bhl[ksl] = __builtin_bit_cast(short8, *(const uint4*)(fragWh + idx + 4));
    }
  }

  // A-frag addressing: row = (lane&7) (MFMA M rows 8-15 duplicate 0-7; their
  // C rows are discarded). 16B chunk = (lane>>4)*16, XOR swizzle row<<4.
  const int arow = lane & 7;
  const int achk = (lane >> 4) << 4;
  const int axr = arow << 4;
  const char* xrowH = (const char*)XH + arow * 1024;
  const char* xrowL = (const char*)XL + arow * 1024;

  f32x4 hh = {0.f, 0.f, 0.f, 0.f}, lh = {0.f, 0.f, 0.f, 0.f}, hl = {0.f, 0.f, 0.f, 0.f};
  float4 xp[2];

  const uint64_t MK2 = 0x4000400040004000ull;
  const uint32_t CM = ~0x40004000u;

#define LOAD_XP(tt)                                                            \
  _Pragma("unroll") for (int i = 0; i < 2; ++i) {                              \
    const int flat4 = i * 2048 + tid * 4;                                      \
    const int row = flat4 >> 9;                                                \
    const int col = flat4 & 511;                                               \
    xp[i] = *(const float4*)(x + ((size_t)(tt) * BB + b0 + row) * DD + col);   \
  }

#define STAGE_XP()                                                             \
  _Pragma("unroll") for (int i = 0; i < 2; ++i) {                              \
    const int flat4 = i * 2048 + tid * 4;                                      \
    const int row = flat4 >> 9;                                                \
    const int col = flat4 & 511;                                               \
    uint16_t h0, l0, h1, l1, h2, l2, h3, l3;                                   \
    split2(xp[i].x, h0, l0);                                                   \
    split2(xp[i].y, h1, l1);                                                   \
    split2(xp[i].z, h2, l2);                                                   \
    split2(xp[i].w, h3, l3);                                                   \
    const uint32_t hw0 = (uint32_t)h0 | ((uint32_t)h1 << 16);                  \
    const uint32_t hw1 = (uint32_t)h2 | ((uint32_t)h3 << 16);                  \
    const uint32_t lw0 = (uint32_t)l0 | ((uint32_t)l1 << 16);                  \
    const uint32_t lw1 = (uint32_t)l2 | ((uint32_t)l3 << 16);                  \
    const int off = row * 1024 + ((col * 2) ^ (row << 4));                     \
    *(uint2*)((char*)XH + off) = make_uint2(hw0, hw1);                         \
    *(uint2*)((char*)XL + off) = make_uint2(lw0, lw1);                         \
  }

#define X_MFMA()                                                               \
  hh = (f32x4){0.f, 0.f, 0.f, 0.f};                                           \
  lh = (f32x4){0.f, 0.f, 0.f, 0.f};                                           \
  hl = (f32x4){0.f, 0.f, 0.f, 0.f};                                           \
  _Pragma("unroll") for (int ksl = 0; ksl < 8; ++ksl) {                        \
    const int off = ((kh * 8 + ksl) * 64 + achk) ^ axr;                        \
    short8 ah = *(const short8*)(xrowH + off);                                 \
    short8 al = *(const short8*)(xrowL + off);                                 \
    hh = __builtin_amdgcn_mfma_f32_16x16x32_bf16(ah, bxh[ksl], hh, 0, 0, 0);   \
    lh = __builtin_amdgcn_mfma_f32_16x16x32_bf16(al, bxh[ksl], lh, 0, 0, 0);   \
    hl = __builtin_amdgcn_mfma_f32_16x16x32_bf16(ah, bxl[ksl], hl, 0, 0, 0);   \
  }

  // ---- prologue: xacc for t=0, prefetch x_1 ----
  LOAD_XP(0);
  __syncthreads();
  STAGE_XP();
  __syncthreads();
  X_MFMA();
  LOAD_XP(1);

  for (int t = 0; t < TT; ++t) {
    const int rbuf = t & 1;
    const int wbuf = rbuf ^ 1;

    if (t > 0) {
      // --- flat poll of tagged h_{t-1}: 4 u64 in flight per probe (R4) ---
      const uint32_t tg = (((uint32_t)(t - 1)) >> 1) & 3u;
      const uint32_t Ed = ((tg & 1u) << 14) | ((tg >> 1) << 30);
      const uint64_t EX2 = ((uint64_t)Ed << 32) | Ed;
      const unsigned long long* pb =
          (const unsigned long long*)(hbase + (size_t)rbuf * (GR * HH)) +
          (size_t)tid * 4;
      uint64_t w0, w1, w2, w3;
      for (;;) {
        w0 = __hip_atomic_load(pb + 0, __ATOMIC_RELAXED, __HIP_MEMORY_SCOPE_AGENT);
        w1 = __hip_atomic_load(pb + 1, __ATOMIC_RELAXED, __HIP_MEMORY_SCOPE_AGENT);
        w2 = __hip_atomic_load(pb + 2, __ATOMIC_RELAXED, __HIP_MEMORY_SCOPE_AGENT);
        w3 = __hip_atomic_load(pb + 3, __ATOMIC_RELAXED, __HIP_MEMORY_SCOPE_AGENT);
        const uint64_t bad =
            (((w0 ^ EX2) | (w1 ^ EX2) | (w2 ^ EX2) | (w3 ^ EX2)) & MK2);
        if (bad == 0ull) break;
      }

      // --- unpack IMMEDIATELY into parity h-tile (no barrier before) ---
      // Safe: HAH/HAL[rbuf]'s last reader was the h-MFMA at t-2 (4 barriers
      // ago). Each thread writes its own 2x16B slots (row = wave).
      {
        uint32_t d0 = (uint32_t)w0 & CM, d1 = (uint32_t)(w0 >> 32) & CM;
        uint32_t d2 = (uint32_t)w1 & CM, d3 = (uint32_t)(w1 >> 32) & CM;
        uint32_t d4 = (uint32_t)w2 & CM, d5 = (uint32_t)(w2 >> 32) & CM;
        uint32_t d6 = (uint32_t)w3 & CM, d7 = (uint32_t)(w3 >> 32) & CM;
        const uint32_t hi0 = (d0 & 0xFFFFu) | (d1 << 16);
        const uint32_t lo0 = (d0 >> 16) | (d1 & 0xFFFF0000u);
        const uint32_t hi1 = (d2 & 0xFFFFu) | (d3 << 16);
        const uint32_t lo1 = (d2 >> 16) | (d3 & 0xFFFF0000u);
        const uint32_t hi2 = (d4 & 0xFFFFu) | (d5 << 16);
        const uint32_t lo2 = (d4 >> 16) | (d5 & 0xFFFF0000u);
        const uint32_t hi3 = (d6 & 0xFFFFu) | (d7 << 16);
        const uint32_t lo3 = (d6 >> 16) | (d7 & 0xFFFF0000u);
        const int woff = wave * 1024 + ((lane * 16) ^ (wave << 4));
        *(uint4*)((char*)HAH[rbuf] + woff) = make_uint4(hi0, hi1, hi2, hi3);
        *(uint4*)((char*)HAL[rbuf] + woff) = make_uint4(lo0, lo1, lo2, lo3);
      }
      __syncthreads();   // single head barrier: h tile ready

      // --- h MFMA (accumulates onto x-projection from prev tail) ---
      {
        const char* rowH = (const char*)HAH[rbuf] + arow * 1024;
        const char* rowL = (const char*)HAL[rbuf] + arow * 1024;
#pragma unroll
        for (int ksl = 0; ksl < 8; ++ksl) {
          const int off = ((kh * 8 + ksl) * 64 + achk) ^ axr;
          short8 ah = *(const short8*)(rowH + off);
          short8 al = *(const short8*)(rowL + off);
          hh = __builtin_amdgcn_mfma_f32_16x16x32_bf16(ah, bhh[ksl], hh, 0, 0, 0);
          lh = __builtin_amdgcn_mfma_f32_16x16x32_bf16(al, bhh[ksl], lh, 0, 0, 0);
          hl = __builtin_amdgcn_mfma_f32_16x16x32_bf16(ah, bhl[ksl], hl, 0, 0, 0);
        }
      }
    }

    // --- exchange partial preacts (C rows 0-7 only) ---
    {
      const int crow = (lane >> 4) << 2;
      const int ccol = lane & 15;
      if (crow < GR) {
#pragma unroll
        for (int r = 0; r < 4; ++r) ex[wave][crow + r][ccol] = hh[r] + lh[r] + hl[r];
      }
    }
    __syncthreads();   // S1: ex ready

    // --- cell update; EARLY tagged h store, then out/state ---
    if (tid < GR * 16) {
      const int brow = tid >> 4;
      const int jc = tid & 15;
      const float p0 = ex[0][brow][jc] + ex[1][brow][jc] + bias_l[0][jc];
      const float p1 = ex[2][brow][jc] + ex[3][brow][jc] + bias_l[1][jc];
      const float p2 = ex[4][brow][jc] + ex[5][brow][jc] + bias_l[2][jc];
      const float p3 = ex[6][brow][jc] + ex[7][brow][jc] + bias_l[3][jc];
      const float ig = sigf(p0);
      const float fg = sigf(p1);
      const float cc = tanh_(p2);
      const float og = sigf(p3);
      const float co = c_st[brow][jc];
      const float ct = fg * co + ig * cc;
      const float ht = og * tanh_(ct);
      const bool m = (t < len_l[brow]);
      const float cn = m ? ct : co;
      const float hn = m ? ht : h_st[brow][jc];
      // early store: visibility to the 31 sibling WGs starts NOW
      uint16_t ph, pl;
      split2(hn, ph, pl);   // |hn| <= 1 -> bit14 of both halves = 0
      const uint32_t tagw = (((uint32_t)t) >> 1) & 3u;
      const uint32_t TB = ((tagw & 1u) << 14) | ((tagw >> 1) << 30);
      __hip_atomic_store(hbase + (size_t)wbuf * (GR * HH) + brow * HH + j0 + jc,
                         ((uint32_t)ph | ((uint32_t)pl << 16)) | TB,
                         __ATOMIC_RELAXED, __HIP_MEMORY_SCOPE_AGENT);
      out[((size_t)t * BB + b0 + brow) * HH + j0 + jc] = m ? ht : 0.0f;
      c_st[brow][jc] = cn;
      h_st[brow][jc] = hn;
    }

    if (t + 1 < TT) {
      STAGE_XP();        // stage x_{t+1} into the dedicated x tile
      __syncthreads();   // S2: x tile staged
      X_MFMA();          // xacc for t+1 — overlaps sibling WG's poll (2/CU)
      LOAD_XP(min(t + 2, TT - 1));
    }
  }
#undef LOAD_XP
#undef STAGE_XP
#undef X_MFMA
}

extern "C" void kernel_launch(void* const* d_in, const int* in_sizes, int n_in,
                              void* d_out, int out_size, void* d_ws, size_t ws_size,
                              hipStream_t stream) {
  const float* x = (const float*)d_in[0];
  const int* len = (const int*)d_in[1];
  const float* Wx = (const float*)d_in[2];    // [2048][512]
  const float* Wh = (const float*)d_in[3];    // [2048][512]
  const float* bias = (const float*)d_in[4];  // [2048]
  float* out = (float*)d_out;

  const size_t FRAG_DW = (size_t)128 * 16 * 64 * 8;   // 4 MB each
  const size_t HP_DW = (size_t)8 * 2 * GR * HH;        // 256 KB
  uint32_t* fragWx = (uint32_t*)d_ws;
  uint32_t* fragWh = fragWx + FRAG_DW;
  uint32_t* h_pair = fragWh + FRAG_DW;
  // total ~8.5 MB; ws proven >= 10.75 MB (R7's lstm3 ran).

  // 0xFF -> tag bits = 3 in every dword: never matches the first expected
  // tags and is overwritten >=2x before tag 3 recurs.
  hipMemsetAsync(h_pair, 0xFF, HP_DW * 4, stream);

  build_frags<<<dim3(512), dim3(256), 0, stream>>>(Wx, fragWx);
  build_frags<<<dim3(512), dim3(256), 0, stream>>>(Wh, fragWh);

  void* args[] = {(void*)&x,      (void*)&len,    (void*)&bias, (void*)&fragWx,
                  (void*)&fragWh, (void*)&h_pair, (void*)&out};
  hipLaunchCooperativeKernel((void*)lstm6, dim3(NWG), dim3(NTHR), args, 0, stream);
}

// Round 11
// 1176.009 us; speedup vs baseline: 2.7273x; 1.2212x over previous
//
#include <hip/hip_runtime.h>
#include <stdint.h>

// LSTM (packed sequence) on MI355X — round 11.
// T=512, B=64, D=512, H=512. out[t,b,:] = masked h_t.
//
// R10 base (256 WGs = 8 groups x 32 jblk, GR=8, 2 WGs/CU, flat 4-u64
// tagged LLC poll, parity h-tile, early h-store) + two changes:
//   1) K-HALF SPLIT EXCHANGE: wave kh consumes only h cols [kh*256,
//      kh*256+256) (produced by jblks kh*16..kh*16+15). kh=0 waves
//      (0,2,4,6) poll+unpack half 0; kh=1 waves half 1. Each half then
//      crosses a 4-wave LDS generation barrier (R8-proven pattern) and
//      starts its h-MFMA immediately: two overlapping max-of-16 waits
//      replace one max-of-32 wait, and each half's MFMA overlaps the
//      other half's detect tail.
//   2) x-tile PARITY DOUBLE-BUFFER: tail(t) stages x(t+2) into XB[t&1]
//      and consumes XB[(t&1)^1] (staged at tail(t-1), separated by the
//      S1 full barrier) -> the S2 barrier is deleted.
// Barriers per step: 1 full (S1) + 1 half (4-wave) vs R10's 3 full.
// Transport unchanged (proven R4-R10): SELF-DESCRIBING TAGGED DATA at
// LLC — bit14/bit30 of each packed (hi,lo) bf16 dword carry a 2-bit step
// tag (|h|<=1 makes those bits provably 0); parity double-buffer; 0xFF
// init = tag 3 never matches first uses.
// bf16 3-split MFMA (hi/lo) both GEMMs: absmax ~3.9e-3 (proven R1-R10).

#define TT 512
#define BB 64
#define DD 512
#define HH 512
#define NWG 256
#define NTHR 512
#define GR 8

typedef short short8 __attribute__((ext_vector_type(8)));
typedef float f32x4 __attribute__((ext_vector_type(4)));

__device__ __forceinline__ uint16_t bf16_rne(float f) {
  uint32_t u = __float_as_uint(f);
  u += 0x7fffu + ((u >> 16) & 1u);
  return (uint16_t)(u >> 16);
}

__device__ __forceinline__ void split2(float f, uint16_t &hi, uint16_t &lo) {
  uint16_t h = bf16_rne(f);
  hi = h;
  lo = bf16_rne(f - __uint_as_float(((uint32_t)h) << 16));
}

__device__ __forceinline__ float sigf(float v) { return 1.0f / (1.0f + __expf(-v)); }
__device__ __forceinline__ float tanh_(float v) {
  return 1.0f - 2.0f / (__expf(2.0f * v) + 1.0f);
}

// Build MFMA B-fragment buffer from W [2048][512] (row-major, k contiguous).
// B-frag lane layout for mfma_f32_16x16x32_bf16: col = lane&15,
// k = ks*32 + (lane>>4)*8 + j (8 contiguous k per lane).
__global__ void build_frags(const float* __restrict__ W, uint32_t* __restrict__ frag) {
  const int tid = blockIdx.x * 256 + threadIdx.x;   // 0..131071
  const int lane = tid & 63;
  const int ks = (tid >> 6) & 15;
  const int nblk = tid >> 10;                        // 0..127
  const int col = nblk * 16 + (lane & 15);
  const int k0 = ks * 32 + ((lane >> 4) << 3);
  const float* src = W + (size_t)col * 512 + k0;
  float4 a = *(const float4*)(src);
  float4 b = *(const float4*)(src + 4);
  float v[8] = {a.x, a.y, a.z, a.w, b.x, b.y, b.z, b.w};
  uint32_t hw[4], lw[4];
#pragma unroll
  for (int j = 0; j < 4; ++j) {
    uint16_t h0, l0, h1, l1;
    split2(v[2 * j], h0, l0);
    split2(v[2 * j + 1], h1, l1);
    hw[j] = (uint32_t)h0 | ((uint32_t)h1 << 16);
    lw[j] = (uint32_t)l0 | ((uint32_t)l1 << 16);
  }
  uint4* dst = (uint4*)(frag + (size_t)tid * 8);
  dst[0] = make_uint4(hw[0], hw[1], hw[2], hw[3]);
  dst[1] = make_uint4(lw[0], lw[1], lw[2], lw[3]);
}

__global__ __launch_bounds__(NTHR, 2) void lstm7(
    const float* __restrict__ x, const int* __restrict__ len,
    const float* __restrict__ bias, const uint32_t* __restrict__ fragWx,
    const uint32_t* __restrict__ fragWh, uint32_t* __restrict__ h_pair,
    float* __restrict__ out) {
  const int tid = threadIdx.x;
  const int lane = tid & 63;
  const int wave = tid >> 6;      // 0..7
  const int gp = wave >> 1;       // gate 0..3 (i,f,c,o)
  const int kh = wave & 1;        // K half (cols kh*256 .. kh*256+255)
  const int group = blockIdx.x & 7;
  const int jblk = blockIdx.x >> 3;   // 0..31
  const int b0 = group * GR;
  const int j0 = jblk << 4;
  uint32_t* hbase = h_pair + (size_t)group * 2 * (GR * HH);

  __shared__ uint16_t HAH[2][GR * 512];   // 16 KB  h tile hi, parity dbuf
  __shared__ uint16_t HAL[2][GR * 512];   // 16 KB  h tile lo
  __shared__ uint16_t XH[2][GR * 512];    // 16 KB  x tile hi, parity dbuf
  __shared__ uint16_t XL[2][GR * 512];    // 16 KB  x tile lo
  __shared__ float ex[8][GR][16];         // 4 KB
  __shared__ float c_st[GR][16];
  __shared__ float h_st[GR][16];
  __shared__ float bias_l[4][16];
  __shared__ int len_l[GR];
  __shared__ uint32_t hcnt[2];            // per-half generation counters

  if (tid < 2) hcnt[tid] = 0u;
  if (tid < GR * 16) {
    c_st[tid >> 4][tid & 15] = 0.0f;
    h_st[tid >> 4][tid & 15] = 0.0f;
  }
  if (tid < 64) bias_l[tid >> 4][tid & 15] = bias[(size_t)(tid >> 4) * HH + j0 + (tid & 15)];
  if (tid < GR) len_l[tid] = len[b0 + tid];

  // Persistent B fragments: this wave's gate, this jblk, its K half.
  short8 bxh[8], bxl[8], bhh[8], bhl[8];
  {
    const int nblk = gp * 32 + jblk;
#pragma unroll
    for (int ksl = 0; ksl < 8; ++ksl) {
      const size_t idx = ((size_t)(nblk * 16 + kh * 8 + ksl) * 64 + lane) * 8;
      bxh[ksl] = __builtin_bit_cast(short8, *(const uint4*)(fragWx + idx));
      bxl[ksl] = __builtin_bit_cast(short8, *(const uint4*)(fragWx + idx + 4));
      bhh[ksl] = __builtin_bit_cast(short8, *(const uint4*)(fragWh + idx));
      bhl[ksl] = __builtin_bit_cast(short8, *(const uint4*)(fragWh + idx + 4));
    }
  }

  // A-frag addressing: row = (lane&7) (MFMA M rows 8-15 duplicate 0-7; their
  // C rows are discarded). 16B chunk = (lane>>4)*16, XOR swizzle row<<4.
  const int arow = lane & 7;
  const int achk = (lane >> 4) << 4;
  const int axr = arow << 4;

  // Poll slice (K-half split): q in [0,256) within this wave's half.
  const int q = ((wave >> 1) << 6) | lane;   // (wave/2)*64 + lane
  const int prow = q >> 5;                   // 0..7
  const int pch = q & 31;                    // 16B chunk within the half

  f32x4 hh = {0.f, 0.f, 0.f, 0.f}, lh = {0.f, 0.f, 0.f, 0.f}, hl = {0.f, 0.f, 0.f, 0.f};
  float4 xp[2];

  const uint64_t MK2 = 0x4000400040004000ull;
  const uint32_t CM = ~0x40004000u;

#define LOAD_XP(tt)                                                            \
  _Pragma("unroll") for (int i = 0; i < 2; ++i) {                              \
    const int flat4 = i * 2048 + tid * 4;                                      \
    const int row = flat4 >> 9;                                                \
    const int col = flat4 & 511;                                               \
    xp[i] = *(const float4*)(x + ((size_t)(tt) * BB + b0 + row) * DD + col);   \
  }

#define STAGE_XP(PB)                                                           \
  _Pragma("unroll") for (int i = 0; i < 2; ++i) {                              \
    const int flat4 = i * 2048 + tid * 4;                                      \
    const int row = flat4 >> 9;                                                \
    const int col = flat4 & 511;                                               \
    uint16_t h0, l0, h1, l1, h2, l2, h3, l3;                                   \
    split2(xp[i].x, h0, l0);                                                   \
    split2(xp[i].y, h1, l1);                                                   \
    split2(xp[i].z, h2, l2);                                                   \
    split2(xp[i].w, h3, l3);                                                   \
    const uint32_t hw0 = (uint32_t)h0 | ((uint32_t)h1 << 16);                  \
    const uint32_t hw1 = (uint32_t)h2 | ((uint32_t)h3 << 16);                  \
    const uint32_t lw0 = (uint32_t)l0 | ((uint32_t)l1 << 16);                  \
    const uint32_t lw1 = (uint32_t)l2 | ((uint32_t)l3 << 16);                  \
    const int off = row * 1024 + ((col * 2) ^ (row << 4));                     \
    *(uint2*)((char*)XH[PB] + off) = make_uint2(hw0, hw1);                     \
    *(uint2*)((char*)XL[PB] + off) = make_uint2(lw0, lw1);                     \
  }

#define X_MFMA(PB)                                                             \
  hh = (f32x4){0.f, 0.f, 0.f, 0.f};                                           \
  lh = (f32x4){0.f, 0.f, 0.f, 0.f};                                           \
  hl = (f32x4){0.f, 0.f, 0.f, 0.f};                                           \
  {                                                                            \
    const char* rH = (const char*)XH[PB] + arow * 1024;                        \
    const char* rL = (const char*)XL[PB] + arow * 1024;                        \
    _Pragma("unroll") for (int ksl = 0; ksl < 8; ++ksl) {                      \
      const int off = ((kh * 8 + ksl) * 64 + achk) ^ axr;                      \
      short8 ah = *(const short8*)(rH + off);                                  \
      short8 al = *(const short8*)(rL + off);                                  \
      hh = __builtin_amdgcn_mfma_f32_16x16x32_bf16(ah, bxh[ksl], hh, 0, 0, 0); \
      lh = __builtin_amdgcn_mfma_f32_16x16x32_bf16(al, bxh[ksl], lh, 0, 0, 0); \
      hl = __builtin_amdgcn_mfma_f32_16x16x32_bf16(ah, bxl[ksl], hl, 0, 0, 0); \
    }                                                                          \
  }

  // ---- prologue: acc = xproj(x_0); XB[1] <- x_1; xp <- x_2 ----
  LOAD_XP(0);
  __syncthreads();   // init (c_st, bias_l, len_l, hcnt) complete
  STAGE_XP(0);
  __syncthreads();   // XB[0] = x_0 staged
  X_MFMA(0);         // acc = xproj(x_0)
  LOAD_XP(1);
  STAGE_XP(1);       // XB[1] = x_1 (consumed at tail(0), after S1(0))
  LOAD_XP(2);

  uint32_t htg = 0;  // half-barrier generation target

  for (int t = 0; t < TT; ++t) {
    const int rbuf = t & 1;
    const int wbuf = rbuf ^ 1;

    if (t > 0) {
      // --- flat poll of this wave's K-HALF of tagged h_{t-1} ---
      const uint32_t tg = (((uint32_t)(t - 1)) >> 1) & 3u;
      const uint32_t Ed = ((tg & 1u) << 14) | ((tg >> 1) << 30);
      const uint64_t EX2 = ((uint64_t)Ed << 32) | Ed;
      const unsigned long long* pb =
          (const unsigned long long*)(hbase + (size_t)rbuf * (GR * HH)) +
          prow * 256 + pch * 4 + (kh ? 128 : 0);
      uint64_t w0, w1, w2, w3;
      for (;;) {
        w0 = __hip_atomic_load(pb + 0, __ATOMIC_RELAXED, __HIP_MEMORY_SCOPE_AGENT);
        w1 = __hip_atomic_load(pb + 1, __ATOMIC_RELAXED, __HIP_MEMORY_SCOPE_AGENT);
        w2 = __hip_atomic_load(pb + 2, __ATOMIC_RELAXED, __HIP_MEMORY_SCOPE_AGENT);
        w3 = __hip_atomic_load(pb + 3, __ATOMIC_RELAXED, __HIP_MEMORY_SCOPE_AGENT);
        const uint64_t bad =
            (((w0 ^ EX2) | (w1 ^ EX2) | (w2 ^ EX2) | (w3 ^ EX2)) & MK2);
        if (bad == 0ull) break;
      }

      // --- unpack into parity h-tile, own half only ---
      // Safe: this region's last readers were this half's waves at t-2,
      // behind the t-2 half-barrier and two S1 barriers.
      {
        uint32_t d0 = (uint32_t)w0 & CM, d1 = (uint32_t)(w0 >> 32) & CM;
        uint32_t d2 = (uint32_t)w1 & CM, d3 = (uint32_t)(w1 >> 32) & CM;
        uint32_t d4 = (uint32_t)w2 & CM, d5 = (uint32_t)(w2 >> 32) & CM;
        uint32_t d6 = (uint32_t)w3 & CM, d7 = (uint32_t)(w3 >> 32) & CM;
        const uint32_t hi0 = (d0 & 0xFFFFu) | (d1 << 16);
        const uint32_t lo0 = (d0 >> 16) | (d1 & 0xFFFF0000u);
        const uint32_t hi1 = (d2 & 0xFFFFu) | (d3 << 16);
        const uint32_t lo1 = (d2 >> 16) | (d3 & 0xFFFF0000u);
        const uint32_t hi2 = (d4 & 0xFFFFu) | (d5 << 16);
        const uint32_t lo2 = (d4 >> 16) | (d5 & 0xFFFF0000u);
        const uint32_t hi3 = (d6 & 0xFFFFu) | (d7 << 16);
        const uint32_t lo3 = (d6 >> 16) | (d7 & 0xFFFF0000u);
        const int woff = prow * 1024 + ((pch * 16 + kh * 512) ^ (prow << 4));
        *(uint4*)((char*)HAH[rbuf] + woff) = make_uint4(hi0, hi1, hi2, hi3);
        *(uint4*)((char*)HAL[rbuf] + woff) = make_uint4(lo0, lo1, lo2, lo3);
      }

      // --- 4-wave half barrier (generation-counted, R8-proven pattern) ---
      htg += 4;
      if (lane == 0)
        __hip_atomic_fetch_add(&hcnt[kh], 1u, __ATOMIC_ACQ_REL,
                               __HIP_MEMORY_SCOPE_WORKGROUP);
      while (__hip_atomic_load(&hcnt[kh], __ATOMIC_ACQUIRE,
                               __HIP_MEMORY_SCOPE_WORKGROUP) < htg) {
      }
      asm volatile("" ::: "memory");

      // --- h MFMA on own K half (accumulates onto x-projection) ---
      {
        const char* rowH = (const char*)HAH[rbuf] + arow * 1024;
        const char* rowL = (const char*)HAL[rbuf] + arow * 1024;
#pragma unroll
        for (int ksl = 0; ksl < 8; ++ksl) {
          const int off = ((kh * 8 + ksl) * 64 + achk) ^ axr;
          short8 ah = *(const short8*)(rowH + off);
          short8 al = *(const short8*)(rowL + off);
          hh = __builtin_amdgcn_mfma_f32_16x16x32_bf16(ah, bhh[ksl], hh, 0, 0, 0);
          lh = __builtin_amdgcn_mfma_f32_16x16x32_bf16(al, bhh[ksl], lh, 0, 0, 0);
          hl = __builtin_amdgcn_mfma_f32_16x16x32_bf16(ah, bhl[ksl], hl, 0, 0, 0);
        }
      }
    }

    // --- exchange partial preacts (C rows 0-7 only) ---
    {
      const int crow = (lane >> 4) << 2;
      const int ccol = lane & 15;
      if (crow < GR) {
#pragma unroll
        for (int r = 0; r < 4; ++r) ex[wave][crow + r][ccol] = hh[r] + lh[r] + hl[r];
      }
    }
    __syncthreads();   // S1: ex ready (also separates x-tile stage/consume)

    // --- cell update; EARLY tagged h store, then out/state ---
    if (tid < GR * 16) {
      const int brow = tid >> 4;
      const int jc = tid & 15;
      const float p0 = ex[0][brow][jc] + ex[1][brow][jc] + bias_l[0][jc];
      const float p1 = ex[2][brow][jc] + ex[3][brow][jc] + bias_l[1][jc];
      const float p2 = ex[4][brow][jc] + ex[5][brow][jc] + bias_l[2][jc];
      const float p3 = ex[6][brow][jc] + ex[7][brow][jc] + bias_l[3][jc];
      const float ig = sigf(p0);
      const float fg = sigf(p1);
      const float cc = tanh_(p2);
      const float og = sigf(p3);
      const float co = c_st[brow][jc];
      const float ct = fg * co + ig * cc;
      const float ht = og * tanh_(ct);
      const bool m = (t < len_l[brow]);
      const float cn = m ? ct : co;
      const float hn = m ? ht : h_st[brow][jc];
      // early store: visibility to the 31 sibling WGs starts NOW
      uint16_t ph, pl;
      split2(hn, ph, pl);   // |hn| <= 1 -> bit14 of both halves = 0
      const uint32_t tagw = (((uint32_t)t) >> 1) & 3u;
      const uint32_t TB = ((tagw & 1u) << 14) | ((tagw >> 1) << 30);
      __hip_atomic_store(hbase + (size_t)wbuf * (GR * HH) + brow * HH + j0 + jc,
                         ((uint32_t)ph | ((uint32_t)pl << 16)) | TB,
                         __ATOMIC_RELAXED, __HIP_MEMORY_SCOPE_AGENT);
      out[((size_t)t * BB + b0 + brow) * HH + j0 + jc] = m ? ht : 0.0f;
      c_st[brow][jc] = cn;
      h_st[brow][jc] = hn;
    }

    if (t + 1 < TT) {
      STAGE_XP(rbuf);        // XB[t&1] <- x_{t+2} (read of XB[t&1] was at
                             // tail(t-1), behind S1(t))
      X_MFMA(wbuf);          // acc = xproj(x_{t+1}) from XB[(t&1)^1],
                             // staged at tail(t-1), behind S1(t)
      LOAD_XP(min(t + 3, TT - 1));
    }
  }
#undef LOAD_XP
#undef STAGE_XP
#undef X_MFMA
}

extern "C" void kernel_launch(void* const* d_in, const int* in_sizes, int n_in,
                              void* d_out, int out_size, void* d_ws, size_t ws_size,
                              hipStream_t stream) {
  const float* x = (const float*)d_in[0];
  const int* len = (const int*)d_in[1];
  const float* Wx = (const float*)d_in[2];    // [2048][512]
  const float* Wh = (const float*)d_in[3];    // [2048][512]
  const float* bias = (const float*)d_in[4];  // [2048]
  float* out = (float*)d_out;

  const size_t FRAG_DW = (size_t)128 * 16 * 64 * 8;   // 4 MB each
  const size_t HP_DW = (size_t)8 * 2 * GR * HH;        // 256 KB
  uint32_t* fragWx = (uint32_t*)d_ws;
  uint32_t* fragWh = fragWx + FRAG_DW;
  uint32_t* h_pair = fragWh + FRAG_DW;
  // total ~8.5 MB; ws proven >= 10.75 MB (R7's lstm3 ran).

  // 0xFF -> tag bits = 3 in every dword: never matches the first expected
  // tags and is overwritten >=2x before tag 3 recurs.
  hipMemsetAsync(h_pair, 0xFF, HP_DW * 4, stream);

  build_frags<<<dim3(512), dim3(256), 0, stream>>>(Wx, fragWx);
  build_frags<<<dim3(512), dim3(256), 0, stream>>>(Wh, fragWh);

  void* args[] = {(void*)&x,      (void*)&len,    (void*)&bias, (void*)&fragWx,
                  (void*)&fragWh, (void*)&h_pair, (void*)&out};
  hipLaunchCooperativeKernel((void*)lstm7, dim3(NWG), dim3(NTHR), args, 0, stream);
}